// Round 8
// baseline (399.793 us; speedup 1.0000x reference)
//
#include <hip/hip_runtime.h>
#include <stdint.h>

#define FIN 256
#define FHID 128
#define BN_EPS 1e-3f

typedef short bf16x8 __attribute__((ext_vector_type(8)));
typedef float f32x4 __attribute__((ext_vector_type(4)));

__device__ inline short f2bf(float f) {
    unsigned u = __float_as_uint(f);
    unsigned r = (u + 0x7FFFu + ((u >> 16) & 1u)) >> 16;   // RNE
    return (short)r;
}
__device__ inline float bflo(unsigned v) { return __uint_as_float(v << 16); }
__device__ inline float bfhi(unsigned v) { return __uint_as_float(v & 0xFFFF0000u); }

#define DEG_SCALE 131072.0f          // 2^17 fixed point
#define DEG_INV   (1.0f / 131072.0f)

// ---------------- W0,W1 -> bf16 transposed [n][k] ----------------
__global__ __launch_bounds__(256) void k_prep_w2(const float* __restrict__ W0,
                                                 const float* __restrict__ W1,
                                                 short* __restrict__ Wt0,
                                                 short* __restrict__ Wt1) {
    int idx = blockIdx.x * 256 + threadIdx.x;
    if (idx < 32768) {            // W0: [256][128] -> Wt0 [128][256]
        int n = idx >> 8, k = idx & 255;
        Wt0[idx] = f2bf(W0[k * 128 + n]);
    } else {
        int j = idx - 32768;      // W1: [128][128] -> Wt1 [128][128]
        if (j < 16384) {
            int n = j >> 7, k = j & 127;
            Wt1[j] = f2bf(W1[k * 128 + n]);
        }
    }
}

// ------- hist (LDS bucket counts) || x -> bf16 convert (both streaming) -----
__global__ __launch_bounds__(256) void k_histcvt(const int* __restrict__ ei, int E,
                                                 int CB, int CHUNK, int nbuk,
                                                 unsigned* __restrict__ bcnt,
                                                 const float* __restrict__ x,
                                                 short* __restrict__ xbf,
                                                 int total4, int cvtThreads) {
    __shared__ unsigned hist[1024];
    if ((int)blockIdx.x < CB) {
        for (int i = threadIdx.x; i < nbuk; i += 256) hist[i] = 0;
        __syncthreads();
        const int e0 = blockIdx.x * CHUNK;
        const int e1 = min(e0 + CHUNK, E);
        for (int e = e0 + threadIdx.x; e < e1; e += 256)
            atomicAdd(&hist[ei[E + e] >> 7], 1u);
        __syncthreads();
        for (int k = threadIdx.x; k < nbuk; k += 256)
            bcnt[(size_t)blockIdx.x * nbuk + k] = hist[k];   // coalesced
    } else {
        int tid = (blockIdx.x - CB) * 256 + threadIdx.x;
        for (int i = tid; i < total4; i += cvtThreads) {
            const float4 v = *reinterpret_cast<const float4*>(x + (size_t)i * 4);
            *reinterpret_cast<short4*>(xbf + (size_t)i * 4) =
                make_short4(f2bf(v.x), f2bf(v.y), f2bf(v.z), f2bf(v.w));
        }
    }
}

// ---------------- GEMM0: bf16 in, A-first ILP ----------------
__global__ __launch_bounds__(256, 2) void k_gemm0(const short* __restrict__ X,
                                                  const short* __restrict__ Wt,
                                                  short* __restrict__ H, int nrows) {
    const int lane = threadIdx.x & 63;
    const int w = threadIdx.x >> 6;
    const int r0 = blockIdx.x * 32;
    const int n0 = w * 32;
    const int l15 = lane & 15;
    const int lk = (lane >> 4) * 8;

    // all 16 independent A-frag loads issued up front (64 VGPRs)
    bf16x8 a[2][8];
#pragma unroll
    for (int mf = 0; mf < 2; mf++) {
        int row = r0 + mf * 16 + l15;
        if (row >= nrows) row = nrows - 1;
        const short* rp = X + (size_t)row * 256 + lk;
#pragma unroll
        for (int ks = 0; ks < 8; ks++)
            a[mf][ks] = *reinterpret_cast<const bf16x8*>(rp + ks * 32);
    }

    f32x4 acc[2][2];
#pragma unroll
    for (int mf = 0; mf < 2; mf++)
#pragma unroll
        for (int nf = 0; nf < 2; nf++)
#pragma unroll
            for (int r = 0; r < 4; r++) acc[mf][nf][r] = 0.0f;

#pragma unroll
    for (int ks = 0; ks < 8; ks++) {
        const bf16x8 b0 = *reinterpret_cast<const bf16x8*>(
            Wt + (size_t)(n0 + l15) * 256 + ks * 32 + lk);
        const bf16x8 b1 = *reinterpret_cast<const bf16x8*>(
            Wt + (size_t)(n0 + 16 + l15) * 256 + ks * 32 + lk);
        acc[0][0] = __builtin_amdgcn_mfma_f32_16x16x32_bf16(a[0][ks], b0, acc[0][0], 0, 0, 0);
        acc[1][0] = __builtin_amdgcn_mfma_f32_16x16x32_bf16(a[1][ks], b0, acc[1][0], 0, 0, 0);
        acc[0][1] = __builtin_amdgcn_mfma_f32_16x16x32_bf16(a[0][ks], b1, acc[0][1], 0, 0, 0);
        acc[1][1] = __builtin_amdgcn_mfma_f32_16x16x32_bf16(a[1][ks], b1, acc[1][1], 0, 0, 0);
    }

#pragma unroll
    for (int mf = 0; mf < 2; mf++) {
        const int rbase = r0 + mf * 16 + (lane >> 4) * 4;
#pragma unroll
        for (int r = 0; r < 4; r++) {
            const int row = rbase + r;
            if (row < nrows) {
#pragma unroll
                for (int nf = 0; nf < 2; nf++)
                    H[(size_t)row * 128 + n0 + nf * 16 + l15] = f2bf(acc[mf][nf][r]);
            }
        }
    }
}

// ---------------- GEMM1: f32 in + BN0+ReLU fused, A-first ILP ----------------
__global__ __launch_bounds__(256, 2) void k_gemm1(const float* __restrict__ X,
                                                  const short* __restrict__ Wt,
                                                  const float* __restrict__ prm,
                                                  short* __restrict__ H, int nrows) {
    const int lane = threadIdx.x & 63;
    const int w = threadIdx.x >> 6;
    const int r0 = blockIdx.x * 32;
    const int n0 = w * 32;
    const int l15 = lane & 15;
    const int lk = (lane >> 4) * 8;

    // all 16 independent 16B f32 loads up front (64 VGPRs)
    float4 u[4][2][2];   // [ks][mf][half]
#pragma unroll
    for (int mf = 0; mf < 2; mf++) {
        int row = r0 + mf * 16 + l15;
        if (row >= nrows) row = nrows - 1;
        const float* rp = X + (size_t)row * 128 + lk;
#pragma unroll
        for (int ks = 0; ks < 4; ks++) {
            u[ks][mf][0] = *reinterpret_cast<const float4*>(rp + ks * 32);
            u[ks][mf][1] = *reinterpret_cast<const float4*>(rp + ks * 32 + 4);
        }
    }

    f32x4 acc[2][2];
#pragma unroll
    for (int mf = 0; mf < 2; mf++)
#pragma unroll
        for (int nf = 0; nf < 2; nf++)
#pragma unroll
            for (int r = 0; r < 4; r++) acc[mf][nf][r] = 0.0f;

#pragma unroll
    for (int ks = 0; ks < 4; ks++) {
        const int kb = ks * 32 + lk;
        const float4 sc0 = *reinterpret_cast<const float4*>(prm + kb);
        const float4 sc1 = *reinterpret_cast<const float4*>(prm + kb + 4);
        const float4 sh0 = *reinterpret_cast<const float4*>(prm + 128 + kb);
        const float4 sh1 = *reinterpret_cast<const float4*>(prm + 128 + kb + 4);
        bf16x8 a[2];
#pragma unroll
        for (int mf = 0; mf < 2; mf++) {
            float4 u0 = u[ks][mf][0], u1 = u[ks][mf][1];
            u0.x = fmaxf(u0.x * sc0.x + sh0.x, 0.f);
            u0.y = fmaxf(u0.y * sc0.y + sh0.y, 0.f);
            u0.z = fmaxf(u0.z * sc0.z + sh0.z, 0.f);
            u0.w = fmaxf(u0.w * sc0.w + sh0.w, 0.f);
            u1.x = fmaxf(u1.x * sc1.x + sh1.x, 0.f);
            u1.y = fmaxf(u1.y * sc1.y + sh1.y, 0.f);
            u1.z = fmaxf(u1.z * sc1.z + sh1.z, 0.f);
            u1.w = fmaxf(u1.w * sc1.w + sh1.w, 0.f);
            bf16x8 t;
            t[0] = f2bf(u0.x); t[1] = f2bf(u0.y); t[2] = f2bf(u0.z); t[3] = f2bf(u0.w);
            t[4] = f2bf(u1.x); t[5] = f2bf(u1.y); t[6] = f2bf(u1.z); t[7] = f2bf(u1.w);
            a[mf] = t;
        }
        const bf16x8 b0 = *reinterpret_cast<const bf16x8*>(
            Wt + (size_t)(n0 + l15) * 128 + kb);
        const bf16x8 b1 = *reinterpret_cast<const bf16x8*>(
            Wt + (size_t)(n0 + 16 + l15) * 128 + kb);
        acc[0][0] = __builtin_amdgcn_mfma_f32_16x16x32_bf16(a[0], b0, acc[0][0], 0, 0, 0);
        acc[1][0] = __builtin_amdgcn_mfma_f32_16x16x32_bf16(a[1], b0, acc[1][0], 0, 0, 0);
        acc[0][1] = __builtin_amdgcn_mfma_f32_16x16x32_bf16(a[0], b1, acc[0][1], 0, 0, 0);
        acc[1][1] = __builtin_amdgcn_mfma_f32_16x16x32_bf16(a[1], b1, acc[1][1], 0, 0, 0);
    }

#pragma unroll
    for (int mf = 0; mf < 2; mf++) {
        const int rbase = r0 + mf * 16 + (lane >> 4) * 4;
#pragma unroll
        for (int r = 0; r < 4; r++) {
            const int row = rbase + r;
            if (row < nrows) {
#pragma unroll
                for (int nf = 0; nf < 2; nf++)
                    H[(size_t)row * 128 + n0 + nf * 16 + l15] = f2bf(acc[mf][nf][r]);
            }
        }
    }
}

// ---------------- phase B: per-bucket scan of block counts (in-place) -------
__global__ __launch_bounds__(256) void k_phaseB(unsigned* __restrict__ bcnt,
                                                unsigned* __restrict__ btotal,
                                                int CB, int nbuk) {
    __shared__ unsigned lds[256];
    const int k = blockIdx.x;   // bucket
    const int t = threadIdx.x;  // block index (CB<=256)
    unsigned v = (t < CB) ? bcnt[(size_t)t * nbuk + k] : 0;
    lds[t] = v;
    __syncthreads();
    for (int off = 1; off < 256; off <<= 1) {
        unsigned add = (t >= off) ? lds[t - off] : 0;
        __syncthreads();
        lds[t] += add;
        __syncthreads();
    }
    if (t < CB) bcnt[(size_t)t * nbuk + k] = lds[t] - v;   // exclusive
    if (t == 255) btotal[k] = lds[255];
}

// ---------------- bucket base scan (single block) ----------------
__global__ __launch_bounds__(256) void k_bsum(const unsigned* __restrict__ btotal,
                                              unsigned* __restrict__ bbase,
                                              int nbuk, int E) {
    __shared__ unsigned lds[256];
    const int t = threadIdx.x;
    unsigned v[4];
    unsigned s = 0;
#pragma unroll
    for (int i = 0; i < 4; i++) {
        int j = t * 4 + i;
        v[i] = (j < nbuk) ? btotal[j] : 0;
        s += v[i];
    }
    lds[t] = s;
    __syncthreads();
    for (int off = 1; off < 256; off <<= 1) {
        unsigned add = (t >= off) ? lds[t - off] : 0;
        __syncthreads();
        lds[t] += add;
        __syncthreads();
    }
    unsigned run = lds[t] - s;
#pragma unroll
    for (int i = 0; i < 4; i++) {
        int j = t * 4 + i;
        if (j < nbuk) bbase[j] = run;
        run += v[i];
    }
    if (t == 255) bbase[nbuk] = (unsigned)E;
}

// ---------------- phase C: bucket-scatter edges (LDS cursors) ----------------
__global__ __launch_bounds__(256) void k_phaseC(const int* __restrict__ ei,
                                                const float* __restrict__ ew,
                                                int E, int CB, int CHUNK, int nbuk,
                                                const unsigned* __restrict__ bcur,
                                                const unsigned* __restrict__ bbase,
                                                int2* __restrict__ recs_mid) {
    __shared__ unsigned curs[1024];
    const int b = blockIdx.x;
    for (int k = threadIdx.x; k < nbuk; k += 256)
        curs[k] = bbase[k] + bcur[(size_t)b * nbuk + k];
    __syncthreads();
    const int e0 = b * CHUNK;
    const int e1 = min(e0 + CHUNK, E);
    for (int e = e0 + threadIdx.x; e < e1; e += 256) {
        int src = ei[e];
        int dst = ei[E + e];
        unsigned pos = atomicAdd(&curs[dst >> 7], 1u);
        recs_mid[pos] = make_int2(src | ((dst & 127) << 17), __float_as_int(ew[e]));
    }
}

// ---------------- phase D: per-bucket dst sort, dinv, rowptr, recs ----------
__global__ __launch_bounds__(256) void k_phaseD(const int2* __restrict__ recs_mid,
                                                const unsigned* __restrict__ bbase,
                                                float* __restrict__ dinv,
                                                int* __restrict__ rowptr,
                                                int2* __restrict__ recs,
                                                int n, int E) {
    __shared__ unsigned cnt[128], wsum[128], rank[128], sc[128], base[128];
    __shared__ float dloc[128];
    const int k = blockIdx.x;
    const int t = threadIdx.x;
    if (t < 128) { cnt[t] = 0; wsum[t] = 0; rank[t] = 0; }
    __syncthreads();
    const unsigned s0 = bbase[k], s1 = bbase[k + 1];
    for (unsigned i = s0 + t; i < s1; i += 256) {
        int2 r = recs_mid[i];
        int dl = (r.x >> 17) & 127;
        atomicAdd(&cnt[dl], 1u);
        atomicAdd(&wsum[dl], (unsigned)(__int_as_float(r.y) * DEG_SCALE));
    }
    __syncthreads();
    if (t < 128) sc[t] = cnt[t];
    __syncthreads();
    for (int off = 1; off < 128; off <<= 1) {
        unsigned add = (t < 128 && t >= off) ? sc[t - off] : 0;
        __syncthreads();
        if (t < 128) sc[t] += add;
        __syncthreads();
    }
    if (t < 128) {
        unsigned excl = sc[t] - cnt[t];
        base[t] = s0 + excl;
        int dst = k * 128 + t;
        if (dst < n) {
            float deg = (float)wsum[t] * DEG_INV + 1.0f;
            float dv = rsqrtf(deg);
            dloc[t] = dv;
            dinv[dst] = dv;
            rowptr[dst] = (int)(s0 + excl);
        }
    }
    if (k == 0 && t == 0) rowptr[n] = E;
    __syncthreads();
    for (unsigned i = s0 + t; i < s1; i += 256) {
        int2 r = recs_mid[i];
        int dl = (r.x >> 17) & 127;
        unsigned rr = atomicAdd(&rank[dl], 1u);
        float w2 = __int_as_float(r.y) * dloc[dl];     // ew * dinv[dst]
        recs[base[dl] + rr] = make_int2(r.x & 0x1FFFF, __float_as_int(w2));
    }
}

// ---------------- phase E: fold dinv[src] into rec weight ----------------
__global__ __launch_bounds__(256) void k_phaseE(int2* __restrict__ recs,
                                                const float* __restrict__ dinv, int E) {
    int i = blockIdx.x * 256 + threadIdx.x;
    if (i < E) {
        int2 r = recs[i];
        float w = __int_as_float(r.y) * dinv[r.x];
        recs[i] = make_int2(r.x, __float_as_int(w));
    }
}

// ---------------- gather + fused stats: 2 edges/wave-instr ----------------
__global__ __launch_bounds__(256) void k_gather_stats(const short* __restrict__ h,
                                                      float* __restrict__ agg,
                                                      const int* __restrict__ rowptr,
                                                      const int2* __restrict__ recs,
                                                      const float* __restrict__ dinv,
                                                      const float* __restrict__ bias,
                                                      float* __restrict__ partial,
                                                      int n, int nwaves) {
    __shared__ float lsum[4][128], lsq[4][128];
    const int w = threadIdx.x >> 6;
    const int lane = threadIdx.x & 63;
    const int half = lane >> 5;          // which edge of the pair
    const int q = lane & 31;             // 4-feature slot within row
    const float4 bv = *reinterpret_cast<const float4*>(bias + q * 4);
    float s0 = 0.f, s1 = 0.f, s2 = 0.f, s3 = 0.f;
    float q0 = 0.f, q1 = 0.f, q2 = 0.f, q3 = 0.f;

    for (int node = blockIdx.x * 4 + w; node < n; node += nwaves) {
        float a0 = 0.f, a1 = 0.f, a2 = 0.f, a3 = 0.f;
        int e = rowptr[node];
        const int end = rowptr[node + 1];
        for (; e + 8 <= end; e += 8) {
            const int2 r0 = recs[e + half];
            const int2 r1 = recs[e + half + 2];
            const int2 r2 = recs[e + half + 4];
            const int2 r3 = recs[e + half + 6];
            const uint2 v0 = *reinterpret_cast<const uint2*>(h + (size_t)r0.x * 128 + q * 4);
            const uint2 v1 = *reinterpret_cast<const uint2*>(h + (size_t)r1.x * 128 + q * 4);
            const uint2 v2 = *reinterpret_cast<const uint2*>(h + (size_t)r2.x * 128 + q * 4);
            const uint2 v3 = *reinterpret_cast<const uint2*>(h + (size_t)r3.x * 128 + q * 4);
            const float w0 = __int_as_float(r0.y);
            const float w1 = __int_as_float(r1.y);
            const float w2 = __int_as_float(r2.y);
            const float w3 = __int_as_float(r3.y);
            a0 += bflo(v0.x) * w0; a1 += bfhi(v0.x) * w0; a2 += bflo(v0.y) * w0; a3 += bfhi(v0.y) * w0;
            a0 += bflo(v1.x) * w1; a1 += bfhi(v1.x) * w1; a2 += bflo(v1.y) * w1; a3 += bfhi(v1.y) * w1;
            a0 += bflo(v2.x) * w2; a1 += bfhi(v2.x) * w2; a2 += bflo(v2.y) * w2; a3 += bfhi(v2.y) * w2;
            a0 += bflo(v3.x) * w3; a1 += bfhi(v3.x) * w3; a2 += bflo(v3.y) * w3; a3 += bfhi(v3.y) * w3;
        }
        for (; e + half < end; e += 2) {
            const int2 r = recs[e + half];
            const uint2 v = *reinterpret_cast<const uint2*>(h + (size_t)r.x * 128 + q * 4);
            const float w0 = __int_as_float(r.y);
            a0 += bflo(v.x) * w0; a1 += bfhi(v.x) * w0; a2 += bflo(v.y) * w0; a3 += bfhi(v.y) * w0;
        }
        a0 += __shfl_xor(a0, 32);
        a1 += __shfl_xor(a1, 32);
        a2 += __shfl_xor(a2, 32);
        a3 += __shfl_xor(a3, 32);
        if (half == 0) {
            const float di = dinv[node];
            const float sl = di * di;
            const uint2 hv = *reinterpret_cast<const uint2*>(h + (size_t)node * 128 + q * 4);
            const float o0 = a0 + bflo(hv.x) * sl + bv.x;
            const float o1 = a1 + bfhi(hv.x) * sl + bv.y;
            const float o2 = a2 + bflo(hv.y) * sl + bv.z;
            const float o3 = a3 + bfhi(hv.y) * sl + bv.w;
            *reinterpret_cast<float4*>(agg + (size_t)node * 128 + q * 4) =
                make_float4(o0, o1, o2, o3);
            s0 += o0; q0 += o0 * o0;
            s1 += o1; q1 += o1 * o1;
            s2 += o2; q2 += o2 * o2;
            s3 += o3; q3 += o3 * o3;
        }
    }

    if (half == 0) {
        *reinterpret_cast<float4*>(&lsum[w][q * 4]) = make_float4(s0, s1, s2, s3);
        *reinterpret_cast<float4*>(&lsq[w][q * 4]) = make_float4(q0, q1, q2, q3);
    }
    __syncthreads();
    const int t = threadIdx.x;
    if (t < 128) {
        float ps = lsum[0][t] + lsum[1][t] + lsum[2][t] + lsum[3][t];
        float pq = lsq[0][t] + lsq[1][t] + lsq[2][t] + lsq[3][t];
        partial[(size_t)blockIdx.x * 256 + t] = ps;
        partial[(size_t)blockIdx.x * 256 + 128 + t] = pq;
    }
}

// ---------------- reduce partials -> stats ----------------
__global__ __launch_bounds__(256) void k_stats_red(const float* __restrict__ partial,
                                                   float* __restrict__ stats, int nblk) {
    const int gid = blockIdx.x * 256 + threadIdx.x;   // grid = 64 blocks
    const int slot = gid & 255;
    const int chunk = gid >> 8;
    const int per = nblk >> 6;
    float v = 0.f;
    for (int p = chunk * per; p < (chunk + 1) * per; p++)
        v += partial[(size_t)p * 256 + slot];
    atomicAdd(&stats[slot], v);
}

__global__ void k_bn_params(const float* __restrict__ stats,
                            const float* __restrict__ g,
                            const float* __restrict__ beta,
                            float* __restrict__ prm, int n) {
    int f = threadIdx.x;
    float inv_n = 1.0f / (float)n;
    float mu = stats[f] * inv_n;
    float var = stats[128 + f] * inv_n - mu * mu;
    float sc = rsqrtf(var + BN_EPS) * g[f];
    prm[f] = sc;
    prm[128 + f] = beta[f] - mu * sc;
}

// ---------------- final BN apply + ReLU (f32 out) ----------------
__global__ __launch_bounds__(256) void k_bn_relu(const float* __restrict__ x,
                                                 float* __restrict__ y,
                                                 const float* __restrict__ prm, int n) {
    int idx = blockIdx.x * blockDim.x + threadIdx.x;
    const int total = n * 32;
    for (; idx < total; idx += gridDim.x * blockDim.x) {
        int node = idx >> 5;
        int c4 = (idx & 31) * 4;
        const float4 xv = *reinterpret_cast<const float4*>(x + (size_t)node * 128 + c4);
        const float4 sc = *reinterpret_cast<const float4*>(prm + c4);
        const float4 sh = *reinterpret_cast<const float4*>(prm + 128 + c4);
        float4 o;
        o.x = fmaxf(xv.x * sc.x + sh.x, 0.f);
        o.y = fmaxf(xv.y * sc.y + sh.y, 0.f);
        o.z = fmaxf(xv.z * sc.z + sh.z, 0.f);
        o.w = fmaxf(xv.w * sc.w + sh.w, 0.f);
        *reinterpret_cast<float4*>(y + (size_t)node * 128 + c4) = o;
    }
}

extern "C" void kernel_launch(void* const* d_in, const int* in_sizes, int n_in,
                              void* d_out, int out_size, void* d_ws, size_t ws_size,
                              hipStream_t stream) {
    const float* x   = (const float*)d_in[0];
    const int*   ei  = (const int*)d_in[1];
    const float* ew  = (const float*)d_in[2];
    const float* W0  = (const float*)d_in[3];
    const float* b0  = (const float*)d_in[4];
    const float* g0  = (const float*)d_in[5];
    const float* be0 = (const float*)d_in[6];
    const float* W1  = (const float*)d_in[7];
    const float* b1  = (const float*)d_in[8];
    const float* g1  = (const float*)d_in[9];
    const float* be1 = (const float*)d_in[10];
    float* out = (float*)d_out;

    const int N = in_sizes[0] / FIN;          // 100000
    const int E = in_sizes[2];                // 1600000
    const int NBUK = (N + 127) >> 7;          // 782
    const int CB = 256;                       // hist chunks (<= 256 for phaseB)
    const int CHUNK = (E + CB - 1) / CB;      // 6250
    const int CVTB = 2048;                    // convert blocks
    const int GB = 2048;                      // gather grid

    // workspace layout
    float* agg      = (float*)d_ws;                          // [N,128] f32
    short* xbf      = (short*)agg;                           // [N,256] bf16 — exact alias
    short* hbf      = (short*)(agg + (size_t)N * 128);       // [N,128] bf16
    int2*  recs     = (int2*)(hbf + (size_t)N * 128);        // [E]
    int2*  recs_mid = recs + E;                              // [E]
    unsigned* bcnt  = (unsigned*)(recs_mid + E);             // [CB*NBUK]
    unsigned* btotal= bcnt + (size_t)CB * NBUK;              // [NBUK]
    unsigned* bbase = btotal + NBUK;                         // [NBUK+1]
    float* dinv     = (float*)(bbase + NBUK + 1);            // [N]
    int*   rowptr   = (int*)(dinv + N);                      // [N+1]
    float* stats    = (float*)(rowptr + N + 1);              // 512
    float* prm      = stats + 512;                           // 256
    float* partial  = prm + 256;                             // [GB*256]

    // Wt staged in d_out (scratch until final bn_relu overwrites)
    short* Wt0 = (short*)d_out;            // [128][256] bf16
    short* Wt1 = Wt0 + 256 * 128;          // [128][128] bf16

    const int gemm_blocks = (N + 31) / 32;
    const int total4 = N * (FIN / 4);          // float4 count of x

    // ---- prep: hist + x->bf16 (streaming), weights, then bf16 GEMM0 ----
    hipMemsetAsync(stats, 0, 512 * sizeof(float), stream);
    k_prep_w2<<<192, 256, 0, stream>>>(W0, W1, Wt0, Wt1);
    k_histcvt<<<CB + CVTB, 256, 0, stream>>>(ei, E, CB, CHUNK, NBUK, bcnt,
                                             x, xbf, total4, CVTB * 256);
    k_gemm0<<<gemm_blocks, 256, 0, stream>>>(xbf, Wt0, hbf, N);

    // ---- CSR build ----
    k_phaseB<<<NBUK, 256, 0, stream>>>(bcnt, btotal, CB, NBUK);
    k_bsum<<<1, 256, 0, stream>>>(btotal, bbase, NBUK, E);
    k_phaseC<<<CB, 256, 0, stream>>>(ei, ew, E, CB, CHUNK, NBUK, bcnt, bbase, recs_mid);
    k_phaseD<<<NBUK, 256, 0, stream>>>(recs_mid, bbase, dinv, rowptr, recs, N, E);
    k_phaseE<<<(E + 255) / 256, 256, 0, stream>>>(recs, dinv, E);

    // ---- layer 0 (gather overwrites xbf region with agg — xbf dead) ----
    k_gather_stats<<<GB, 256, 0, stream>>>(hbf, agg, rowptr, recs, dinv, b0,
                                           partial, N, GB * 4);
    k_stats_red<<<64, 256, 0, stream>>>(partial, stats, GB);
    k_bn_params<<<1, 128, 0, stream>>>(stats, g0, be0, prm, N);

    // ---- layer 1 (BN0+ReLU fused into GEMM A-load) ----
    k_gemm1<<<gemm_blocks, 256, 0, stream>>>(agg, Wt1, prm, hbf, N);
    k_gather_stats<<<GB, 256, 0, stream>>>(hbf, agg, rowptr, recs, dinv, b1,
                                           partial, N, GB * 4);
    k_stats_red<<<64, 256, 0, stream>>>(partial, stats + 256, GB);
    k_bn_params<<<1, 128, 0, stream>>>(stats + 256, g1, be1, prm, N);
    k_bn_relu<<<2048, 256, 0, stream>>>(agg, out, prm, N);
}

// Round 9
// 391.217 us; speedup vs baseline: 1.0219x; 1.0219x over previous
//
#include <hip/hip_runtime.h>
#include <stdint.h>

#define FIN 256
#define FHID 128
#define BN_EPS 1e-3f

typedef short bf16x8 __attribute__((ext_vector_type(8)));
typedef float f32x4 __attribute__((ext_vector_type(4)));

__device__ inline short f2bf(float f) {
    unsigned u = __float_as_uint(f);
    unsigned r = (u + 0x7FFFu + ((u >> 16) & 1u)) >> 16;   // RNE
    return (short)r;
}
__device__ inline float bflo(unsigned v) { return __uint_as_float(v << 16); }
__device__ inline float bfhi(unsigned v) { return __uint_as_float(v & 0xFFFF0000u); }
__device__ inline float bf2f(short s) {
    return __uint_as_float(((unsigned)(unsigned short)s) << 16);
}

#define DEG_SCALE 131072.0f          // 2^17 fixed point
#define DEG_INV   (1.0f / 131072.0f)

// ------- hist (LDS bucket counts) || W0,W1 -> bf16 transposed ----------------
__global__ __launch_bounds__(256) void k_histprep(const int* __restrict__ ei, int E,
                                                  int CB, int CHUNK, int nbuk,
                                                  unsigned* __restrict__ bcnt,
                                                  const float* __restrict__ W0,
                                                  const float* __restrict__ W1,
                                                  short* __restrict__ Wt0,
                                                  short* __restrict__ Wt1) {
    __shared__ unsigned hist[1024];
    if ((int)blockIdx.x < CB) {
        for (int i = threadIdx.x; i < nbuk; i += 256) hist[i] = 0;
        __syncthreads();
        const int e0 = blockIdx.x * CHUNK;
        const int e1 = min(e0 + CHUNK, E);
        for (int e = e0 + threadIdx.x; e < e1; e += 256)
            atomicAdd(&hist[ei[E + e] >> 7], 1u);
        __syncthreads();
        for (int k = threadIdx.x; k < nbuk; k += 256)
            bcnt[(size_t)blockIdx.x * nbuk + k] = hist[k];
    } else {
        int idx = ((int)blockIdx.x - CB) * 256 + threadIdx.x;
        if (idx < 32768) {            // W0: [256][128] -> Wt0 [128][256]
            int n = idx >> 8, k = idx & 255;
            Wt0[idx] = f2bf(W0[k * 128 + n]);
        } else {
            int j = idx - 32768;      // W1: [128][128] -> Wt1 [128][128]
            if (j < 16384) {
                int n = j >> 7, k = j & 127;
                Wt1[j] = f2bf(W1[k * 128 + n]);
            }
        }
    }
}

// ---------------- GEMM0: f32 x in, chunked A-prefetch ----------------
__global__ __launch_bounds__(256, 2) void k_gemm0(const float* __restrict__ X,
                                                  const short* __restrict__ Wt,
                                                  short* __restrict__ H, int nrows) {
    const int lane = threadIdx.x & 63;
    const int w = threadIdx.x >> 6;
    const int r0 = blockIdx.x * 32;
    const int n0 = w * 32;
    const int l15 = lane & 15;
    const int lk = (lane >> 4) * 8;

    int row0 = r0 + l15;        if (row0 >= nrows) row0 = nrows - 1;
    int row1 = r0 + 16 + l15;   if (row1 >= nrows) row1 = nrows - 1;
    const float* rp[2] = { X + (size_t)row0 * 256 + lk, X + (size_t)row1 * 256 + lk };

    f32x4 acc[2][2];
#pragma unroll
    for (int mf = 0; mf < 2; mf++)
#pragma unroll
        for (int nf = 0; nf < 2; nf++)
#pragma unroll
            for (int r = 0; r < 4; r++) acc[mf][nf][r] = 0.0f;

#pragma unroll
    for (int ch = 0; ch < 2; ch++) {
        float4 u[4][2][2];   // [c][mf][half] — 16 loads in flight
#pragma unroll
        for (int mf = 0; mf < 2; mf++)
#pragma unroll
            for (int c = 0; c < 4; c++) {
                u[c][mf][0] = *reinterpret_cast<const float4*>(rp[mf] + (ch * 4 + c) * 32);
                u[c][mf][1] = *reinterpret_cast<const float4*>(rp[mf] + (ch * 4 + c) * 32 + 4);
            }
#pragma unroll
        for (int c = 0; c < 4; c++) {
            const int ks = ch * 4 + c;
            bf16x8 a[2];
#pragma unroll
            for (int mf = 0; mf < 2; mf++) {
                const float4 u0 = u[c][mf][0], u1 = u[c][mf][1];
                bf16x8 t;
                t[0] = f2bf(u0.x); t[1] = f2bf(u0.y); t[2] = f2bf(u0.z); t[3] = f2bf(u0.w);
                t[4] = f2bf(u1.x); t[5] = f2bf(u1.y); t[6] = f2bf(u1.z); t[7] = f2bf(u1.w);
                a[mf] = t;
            }
            const bf16x8 b0 = *reinterpret_cast<const bf16x8*>(
                Wt + (size_t)(n0 + l15) * 256 + ks * 32 + lk);
            const bf16x8 b1 = *reinterpret_cast<const bf16x8*>(
                Wt + (size_t)(n0 + 16 + l15) * 256 + ks * 32 + lk);
            acc[0][0] = __builtin_amdgcn_mfma_f32_16x16x32_bf16(a[0], b0, acc[0][0], 0, 0, 0);
            acc[1][0] = __builtin_amdgcn_mfma_f32_16x16x32_bf16(a[1], b0, acc[1][0], 0, 0, 0);
            acc[0][1] = __builtin_amdgcn_mfma_f32_16x16x32_bf16(a[0], b1, acc[0][1], 0, 0, 0);
            acc[1][1] = __builtin_amdgcn_mfma_f32_16x16x32_bf16(a[1], b1, acc[1][1], 0, 0, 0);
        }
    }

#pragma unroll
    for (int mf = 0; mf < 2; mf++) {
        const int rbase = r0 + mf * 16 + (lane >> 4) * 4;
#pragma unroll
        for (int r = 0; r < 4; r++) {
            const int row = rbase + r;
            if (row < nrows) {
#pragma unroll
                for (int nf = 0; nf < 2; nf++)
                    H[(size_t)row * 128 + n0 + nf * 16 + l15] = f2bf(acc[mf][nf][r]);
            }
        }
    }
}

// ---------------- GEMM1: bf16 agg in + BN0+ReLU fused ----------------
__global__ __launch_bounds__(256, 2) void k_gemm1(const short* __restrict__ X,
                                                  const short* __restrict__ Wt,
                                                  const float* __restrict__ prm,
                                                  short* __restrict__ H, int nrows) {
    const int lane = threadIdx.x & 63;
    const int w = threadIdx.x >> 6;
    const int r0 = blockIdx.x * 32;
    const int n0 = w * 32;
    const int l15 = lane & 15;
    const int lk = (lane >> 4) * 8;

    // all 8 A-frag bf16 loads up front
    bf16x8 araw[4][2];
#pragma unroll
    for (int mf = 0; mf < 2; mf++) {
        int row = r0 + mf * 16 + l15;
        if (row >= nrows) row = nrows - 1;
        const short* rp = X + (size_t)row * 128 + lk;
#pragma unroll
        for (int ks = 0; ks < 4; ks++)
            araw[ks][mf] = *reinterpret_cast<const bf16x8*>(rp + ks * 32);
    }

    f32x4 acc[2][2];
#pragma unroll
    for (int mf = 0; mf < 2; mf++)
#pragma unroll
        for (int nf = 0; nf < 2; nf++)
#pragma unroll
            for (int r = 0; r < 4; r++) acc[mf][nf][r] = 0.0f;

#pragma unroll
    for (int ks = 0; ks < 4; ks++) {
        const int kb = ks * 32 + lk;
        const float4 sc0 = *reinterpret_cast<const float4*>(prm + kb);
        const float4 sc1 = *reinterpret_cast<const float4*>(prm + kb + 4);
        const float4 sh0 = *reinterpret_cast<const float4*>(prm + 128 + kb);
        const float4 sh1 = *reinterpret_cast<const float4*>(prm + 128 + kb + 4);
        bf16x8 a[2];
#pragma unroll
        for (int mf = 0; mf < 2; mf++) {
            const bf16x8 ar = araw[ks][mf];
            bf16x8 t;
            t[0] = f2bf(fmaxf(bf2f(ar[0]) * sc0.x + sh0.x, 0.f));
            t[1] = f2bf(fmaxf(bf2f(ar[1]) * sc0.y + sh0.y, 0.f));
            t[2] = f2bf(fmaxf(bf2f(ar[2]) * sc0.z + sh0.z, 0.f));
            t[3] = f2bf(fmaxf(bf2f(ar[3]) * sc0.w + sh0.w, 0.f));
            t[4] = f2bf(fmaxf(bf2f(ar[4]) * sc1.x + sh1.x, 0.f));
            t[5] = f2bf(fmaxf(bf2f(ar[5]) * sc1.y + sh1.y, 0.f));
            t[6] = f2bf(fmaxf(bf2f(ar[6]) * sc1.z + sh1.z, 0.f));
            t[7] = f2bf(fmaxf(bf2f(ar[7]) * sc1.w + sh1.w, 0.f));
            a[mf] = t;
        }
        const bf16x8 b0 = *reinterpret_cast<const bf16x8*>(
            Wt + (size_t)(n0 + l15) * 128 + kb);
        const bf16x8 b1 = *reinterpret_cast<const bf16x8*>(
            Wt + (size_t)(n0 + 16 + l15) * 128 + kb);
        acc[0][0] = __builtin_amdgcn_mfma_f32_16x16x32_bf16(a[0], b0, acc[0][0], 0, 0, 0);
        acc[1][0] = __builtin_amdgcn_mfma_f32_16x16x32_bf16(a[1], b0, acc[1][0], 0, 0, 0);
        acc[0][1] = __builtin_amdgcn_mfma_f32_16x16x32_bf16(a[0], b1, acc[0][1], 0, 0, 0);
        acc[1][1] = __builtin_amdgcn_mfma_f32_16x16x32_bf16(a[1], b1, acc[1][1], 0, 0, 0);
    }

#pragma unroll
    for (int mf = 0; mf < 2; mf++) {
        const int rbase = r0 + mf * 16 + (lane >> 4) * 4;
#pragma unroll
        for (int r = 0; r < 4; r++) {
            const int row = rbase + r;
            if (row < nrows) {
#pragma unroll
                for (int nf = 0; nf < 2; nf++)
                    H[(size_t)row * 128 + n0 + nf * 16 + l15] = f2bf(acc[mf][nf][r]);
            }
        }
    }
}

// ---------------- phase B: per-bucket scan of block counts (in-place) -------
__global__ __launch_bounds__(256) void k_phaseB(unsigned* __restrict__ bcnt,
                                                unsigned* __restrict__ btotal,
                                                int CB, int nbuk) {
    __shared__ unsigned lds[256];
    const int k = blockIdx.x;
    const int t = threadIdx.x;
    unsigned v = (t < CB) ? bcnt[(size_t)t * nbuk + k] : 0;
    lds[t] = v;
    __syncthreads();
    for (int off = 1; off < 256; off <<= 1) {
        unsigned add = (t >= off) ? lds[t - off] : 0;
        __syncthreads();
        lds[t] += add;
        __syncthreads();
    }
    if (t < CB) bcnt[(size_t)t * nbuk + k] = lds[t] - v;
    if (t == 255) btotal[k] = lds[255];
}

// ---------------- bucket base scan (single block) ----------------
__global__ __launch_bounds__(256) void k_bsum(const unsigned* __restrict__ btotal,
                                              unsigned* __restrict__ bbase,
                                              int nbuk, int E) {
    __shared__ unsigned lds[256];
    const int t = threadIdx.x;
    unsigned v[4];
    unsigned s = 0;
#pragma unroll
    for (int i = 0; i < 4; i++) {
        int j = t * 4 + i;
        v[i] = (j < nbuk) ? btotal[j] : 0;
        s += v[i];
    }
    lds[t] = s;
    __syncthreads();
    for (int off = 1; off < 256; off <<= 1) {
        unsigned add = (t >= off) ? lds[t - off] : 0;
        __syncthreads();
        lds[t] += add;
        __syncthreads();
    }
    unsigned run = lds[t] - s;
#pragma unroll
    for (int i = 0; i < 4; i++) {
        int j = t * 4 + i;
        if (j < nbuk) bbase[j] = run;
        run += v[i];
    }
    if (t == 255) bbase[nbuk] = (unsigned)E;
}

// ---------------- phase C: bucket-scatter edges (LDS cursors) ----------------
__global__ __launch_bounds__(256) void k_phaseC(const int* __restrict__ ei,
                                                const float* __restrict__ ew,
                                                int E, int CB, int CHUNK, int nbuk,
                                                const unsigned* __restrict__ bcur,
                                                const unsigned* __restrict__ bbase,
                                                int2* __restrict__ recs_mid) {
    __shared__ unsigned curs[1024];
    const int b = blockIdx.x;
    for (int k = threadIdx.x; k < nbuk; k += 256)
        curs[k] = bbase[k] + bcur[(size_t)b * nbuk + k];
    __syncthreads();
    const int e0 = b * CHUNK;
    const int e1 = min(e0 + CHUNK, E);
    for (int e = e0 + threadIdx.x; e < e1; e += 256) {
        int src = ei[e];
        int dst = ei[E + e];
        unsigned pos = atomicAdd(&curs[dst >> 7], 1u);
        recs_mid[pos] = make_int2(src | ((dst & 127) << 17), __float_as_int(ew[e]));
    }
}

// ---------------- phase D: per-bucket dst sort, dinv, rowptr, recs ----------
__global__ __launch_bounds__(256) void k_phaseD(const int2* __restrict__ recs_mid,
                                                const unsigned* __restrict__ bbase,
                                                float* __restrict__ dinv,
                                                int* __restrict__ rowptr,
                                                int2* __restrict__ recs,
                                                int n, int E) {
    __shared__ unsigned cnt[128], wsum[128], rank[128], sc[128], base[128];
    __shared__ float dloc[128];
    const int k = blockIdx.x;
    const int t = threadIdx.x;
    if (t < 128) { cnt[t] = 0; wsum[t] = 0; rank[t] = 0; }
    __syncthreads();
    const unsigned s0 = bbase[k], s1 = bbase[k + 1];
    for (unsigned i = s0 + t; i < s1; i += 256) {
        int2 r = recs_mid[i];
        int dl = (r.x >> 17) & 127;
        atomicAdd(&cnt[dl], 1u);
        atomicAdd(&wsum[dl], (unsigned)(__int_as_float(r.y) * DEG_SCALE));
    }
    __syncthreads();
    if (t < 128) sc[t] = cnt[t];
    __syncthreads();
    for (int off = 1; off < 128; off <<= 1) {
        unsigned add = (t < 128 && t >= off) ? sc[t - off] : 0;
        __syncthreads();
        if (t < 128) sc[t] += add;
        __syncthreads();
    }
    if (t < 128) {
        unsigned excl = sc[t] - cnt[t];
        base[t] = s0 + excl;
        int dst = k * 128 + t;
        if (dst < n) {
            float deg = (float)wsum[t] * DEG_INV + 1.0f;
            float dv = rsqrtf(deg);
            dloc[t] = dv;
            dinv[dst] = dv;
            rowptr[dst] = (int)(s0 + excl);
        }
    }
    if (k == 0 && t == 0) rowptr[n] = E;
    __syncthreads();
    for (unsigned i = s0 + t; i < s1; i += 256) {
        int2 r = recs_mid[i];
        int dl = (r.x >> 17) & 127;
        unsigned rr = atomicAdd(&rank[dl], 1u);
        float w2 = __int_as_float(r.y) * dloc[dl];     // ew * dinv[dst]
        recs[base[dl] + rr] = make_int2(r.x & 0x1FFFF, __float_as_int(w2));
    }
}

// ---------------- phase E: fold dinv[src] into rec weight ----------------
__global__ __launch_bounds__(256) void k_phaseE(int2* __restrict__ recs,
                                                const float* __restrict__ dinv, int E) {
    int i = blockIdx.x * 256 + threadIdx.x;
    if (i < E) {
        int2 r = recs[i];
        float w = __int_as_float(r.y) * dinv[r.x];
        recs[i] = make_int2(r.x, __float_as_int(w));
    }
}

// ------- gather + stats: quarter-wave rows (uint4/lane), 4 edges/instr ------
__global__ __launch_bounds__(256) void k_gather_stats(const short* __restrict__ h,
                                                      short* __restrict__ aggbf,
                                                      const int* __restrict__ rowptr,
                                                      const int2* __restrict__ recs,
                                                      const float* __restrict__ dinv,
                                                      const float* __restrict__ bias,
                                                      float* __restrict__ partial,
                                                      int n, int nwaves) {
    __shared__ float lsum[4][128], lsq[4][128];
    const int w = threadIdx.x >> 6;
    const int lane = threadIdx.x & 63;
    const int q3 = lane >> 4;            // edge slot 0..3
    const int ql = lane & 15;            // feature group: [ql*8, ql*8+8)
    const int f8 = ql * 8;
    float s[8], qq[8];
#pragma unroll
    for (int j = 0; j < 8; j++) { s[j] = 0.f; qq[j] = 0.f; }

    for (int node = blockIdx.x * 4 + w; node < n; node += nwaves) {
        float a[8];
#pragma unroll
        for (int j = 0; j < 8; j++) a[j] = 0.f;
        int e = rowptr[node];
        const int end = rowptr[node + 1];
        for (; e + 8 <= end; e += 8) {
            const int2 r0 = recs[e + q3];
            const int2 r1 = recs[e + q3 + 4];
            const uint4 v0 = *reinterpret_cast<const uint4*>(h + (size_t)r0.x * 128 + f8);
            const uint4 v1 = *reinterpret_cast<const uint4*>(h + (size_t)r1.x * 128 + f8);
            const float w0 = __int_as_float(r0.y);
            const float w1 = __int_as_float(r1.y);
            a[0] += bflo(v0.x) * w0; a[1] += bfhi(v0.x) * w0;
            a[2] += bflo(v0.y) * w0; a[3] += bfhi(v0.y) * w0;
            a[4] += bflo(v0.z) * w0; a[5] += bfhi(v0.z) * w0;
            a[6] += bflo(v0.w) * w0; a[7] += bfhi(v0.w) * w0;
            a[0] += bflo(v1.x) * w1; a[1] += bfhi(v1.x) * w1;
            a[2] += bflo(v1.y) * w1; a[3] += bfhi(v1.y) * w1;
            a[4] += bflo(v1.z) * w1; a[5] += bfhi(v1.z) * w1;
            a[6] += bflo(v1.w) * w1; a[7] += bfhi(v1.w) * w1;
        }
        for (; e + q3 < end; e += 4) {
            const int2 r = recs[e + q3];
            const uint4 v = *reinterpret_cast<const uint4*>(h + (size_t)r.x * 128 + f8);
            const float w0 = __int_as_float(r.y);
            a[0] += bflo(v.x) * w0; a[1] += bfhi(v.x) * w0;
            a[2] += bflo(v.y) * w0; a[3] += bfhi(v.y) * w0;
            a[4] += bflo(v.z) * w0; a[5] += bfhi(v.z) * w0;
            a[6] += bflo(v.w) * w0; a[7] += bfhi(v.w) * w0;
        }
#pragma unroll
        for (int j = 0; j < 8; j++) {
            a[j] += __shfl_xor(a[j], 16);
            a[j] += __shfl_xor(a[j], 32);
        }
        if (q3 == 0) {
            const float di = dinv[node];
            const float sl = di * di;
            const uint4 hv = *reinterpret_cast<const uint4*>(h + (size_t)node * 128 + f8);
            const float4 bv0 = *reinterpret_cast<const float4*>(bias + f8);
            const float4 bv1 = *reinterpret_cast<const float4*>(bias + f8 + 4);
            float o[8];
            o[0] = a[0] + bflo(hv.x) * sl + bv0.x;
            o[1] = a[1] + bfhi(hv.x) * sl + bv0.y;
            o[2] = a[2] + bflo(hv.y) * sl + bv0.z;
            o[3] = a[3] + bfhi(hv.y) * sl + bv0.w;
            o[4] = a[4] + bflo(hv.z) * sl + bv1.x;
            o[5] = a[5] + bfhi(hv.z) * sl + bv1.y;
            o[6] = a[6] + bflo(hv.w) * sl + bv1.z;
            o[7] = a[7] + bfhi(hv.w) * sl + bv1.w;
            bf16x8 ob;
#pragma unroll
            for (int j = 0; j < 8; j++) ob[j] = f2bf(o[j]);
            *reinterpret_cast<bf16x8*>(aggbf + (size_t)node * 128 + f8) = ob;
#pragma unroll
            for (int j = 0; j < 8; j++) { s[j] += o[j]; qq[j] += o[j] * o[j]; }
        }
    }

    if (q3 == 0) {
#pragma unroll
        for (int j = 0; j < 8; j++) { lsum[w][f8 + j] = s[j]; lsq[w][f8 + j] = qq[j]; }
    }
    __syncthreads();
    const int t = threadIdx.x;
    if (t < 128) {
        float ps = lsum[0][t] + lsum[1][t] + lsum[2][t] + lsum[3][t];
        float pq = lsq[0][t] + lsq[1][t] + lsq[2][t] + lsq[3][t];
        partial[(size_t)blockIdx.x * 256 + t] = ps;
        partial[(size_t)blockIdx.x * 256 + 128 + t] = pq;
    }
}

// -------- stats reduce + BN params in one kernel (block = feature) ----------
__global__ __launch_bounds__(256) void k_stats_bn(const float* __restrict__ partial,
                                                  const float* __restrict__ g,
                                                  const float* __restrict__ beta,
                                                  float* __restrict__ prm,
                                                  int nblk, int n) {
    __shared__ float wsm[4], wqm[4];
    const int f = blockIdx.x;            // 0..127
    const int t = threadIdx.x;
    const int per = nblk / 256;          // 8
    float s = 0.f, q = 0.f;
    for (int i = 0; i < per; i++) {
        int p = t * per + i;
        s += partial[(size_t)p * 256 + f];
        q += partial[(size_t)p * 256 + 128 + f];
    }
#pragma unroll
    for (int off = 1; off < 64; off <<= 1) {
        s += __shfl_xor(s, off);
        q += __shfl_xor(q, off);
    }
    if ((t & 63) == 0) { wsm[t >> 6] = s; wqm[t >> 6] = q; }
    __syncthreads();
    if (t == 0) {
        float S = wsm[0] + wsm[1] + wsm[2] + wsm[3];
        float Q = wqm[0] + wqm[1] + wqm[2] + wqm[3];
        float inv_n = 1.0f / (float)n;
        float mu = S * inv_n;
        float var = Q * inv_n - mu * mu;
        float sc = rsqrtf(var + BN_EPS) * g[f];
        prm[f] = sc;
        prm[128 + f] = beta[f] - mu * sc;
    }
}

// ---------------- final BN apply + ReLU (bf16 agg -> f32 out) ----------------
__global__ __launch_bounds__(256) void k_bn_relu(const short* __restrict__ xbf,
                                                 float* __restrict__ y,
                                                 const float* __restrict__ prm, int n) {
    int idx = blockIdx.x * blockDim.x + threadIdx.x;
    const int total = n * 16;
    for (; idx < total; idx += gridDim.x * blockDim.x) {
        int node = idx >> 4;
        int f8 = (idx & 15) * 8;
        const uint4 v = *reinterpret_cast<const uint4*>(xbf + (size_t)node * 128 + f8);
        const float4 sc0 = *reinterpret_cast<const float4*>(prm + f8);
        const float4 sc1 = *reinterpret_cast<const float4*>(prm + f8 + 4);
        const float4 sh0 = *reinterpret_cast<const float4*>(prm + 128 + f8);
        const float4 sh1 = *reinterpret_cast<const float4*>(prm + 128 + f8 + 4);
        float4 o0, o1;
        o0.x = fmaxf(bflo(v.x) * sc0.x + sh0.x, 0.f);
        o0.y = fmaxf(bfhi(v.x) * sc0.y + sh0.y, 0.f);
        o0.z = fmaxf(bflo(v.y) * sc0.z + sh0.z, 0.f);
        o0.w = fmaxf(bfhi(v.y) * sc0.w + sh0.w, 0.f);
        o1.x = fmaxf(bflo(v.z) * sc1.x + sh1.x, 0.f);
        o1.y = fmaxf(bfhi(v.z) * sc1.y + sh1.y, 0.f);
        o1.z = fmaxf(bflo(v.w) * sc1.z + sh1.z, 0.f);
        o1.w = fmaxf(bfhi(v.w) * sc1.w + sh1.w, 0.f);
        float* yp = y + (size_t)node * 128 + f8;
        *reinterpret_cast<float4*>(yp) = o0;
        *reinterpret_cast<float4*>(yp + 4) = o1;
    }
}

extern "C" void kernel_launch(void* const* d_in, const int* in_sizes, int n_in,
                              void* d_out, int out_size, void* d_ws, size_t ws_size,
                              hipStream_t stream) {
    const float* x   = (const float*)d_in[0];
    const int*   ei  = (const int*)d_in[1];
    const float* ew  = (const float*)d_in[2];
    const float* W0  = (const float*)d_in[3];
    const float* b0  = (const float*)d_in[4];
    const float* g0  = (const float*)d_in[5];
    const float* be0 = (const float*)d_in[6];
    const float* W1  = (const float*)d_in[7];
    const float* b1  = (const float*)d_in[8];
    const float* g1  = (const float*)d_in[9];
    const float* be1 = (const float*)d_in[10];
    float* out = (float*)d_out;

    const int N = in_sizes[0] / FIN;          // 100000
    const int E = in_sizes[2];                // 1600000
    const int NBUK = (N + 127) >> 7;          // 782
    const int CB = 256;                       // hist chunks (<= 256 for phaseB)
    const int CHUNK = (E + CB - 1) / CB;      // 6250
    const int GB = 2048;                      // gather grid

    // workspace layout
    short* aggbf    = (short*)d_ws;                          // [N,128] bf16
    short* hbf      = aggbf + (size_t)N * 128;               // [N,128] bf16
    int2*  recs     = (int2*)(hbf + (size_t)N * 128);        // [E]
    int2*  recs_mid = recs + E;                              // [E]
    unsigned* bcnt  = (unsigned*)(recs_mid + E);             // [CB*NBUK]
    unsigned* btotal= bcnt + (size_t)CB * NBUK;              // [NBUK]
    unsigned* bbase = btotal + NBUK;                         // [NBUK+1]
    float* dinv     = (float*)(bbase + NBUK + 1);            // [N]
    int*   rowptr   = (int*)(dinv + N);                      // [N+1]
    float* prm      = (float*)(rowptr + N + 1);              // 256
    float* partial  = prm + 256;                             // [GB*256]

    // Wt staged in d_out (scratch until final bn_relu overwrites)
    short* Wt0 = (short*)d_out;            // [128][256] bf16
    short* Wt1 = Wt0 + 256 * 128;          // [128][128] bf16

    const int gemm_blocks = (N + 31) / 32;

    // ---- hist + weight prep, then GEMM0 straight from f32 x ----
    k_histprep<<<CB + 192, 256, 0, stream>>>(ei, E, CB, CHUNK, NBUK, bcnt,
                                             W0, W1, Wt0, Wt1);
    k_gemm0<<<gemm_blocks, 256, 0, stream>>>(x, Wt0, hbf, N);

    // ---- CSR build ----
    k_phaseB<<<NBUK, 256, 0, stream>>>(bcnt, btotal, CB, NBUK);
    k_bsum<<<1, 256, 0, stream>>>(btotal, bbase, NBUK, E);
    k_phaseC<<<CB, 256, 0, stream>>>(ei, ew, E, CB, CHUNK, NBUK, bcnt, bbase, recs_mid);
    k_phaseD<<<NBUK, 256, 0, stream>>>(recs_mid, bbase, dinv, rowptr, recs, N, E);
    k_phaseE<<<(E + 255) / 256, 256, 0, stream>>>(recs, dinv, E);

    // ---- layer 0 ----
    k_gather_stats<<<GB, 256, 0, stream>>>(hbf, aggbf, rowptr, recs, dinv, b0,
                                           partial, N, GB * 4);
    k_stats_bn<<<128, 256, 0, stream>>>(partial, g0, be0, prm, GB, N);

    // ---- layer 1 ----
    k_gemm1<<<gemm_blocks, 256, 0, stream>>>(aggbf, Wt1, prm, hbf, N);
    k_gather_stats<<<GB, 256, 0, stream>>>(hbf, aggbf, rowptr, recs, dinv, b1,
                                           partial, N, GB * 4);
    k_stats_bn<<<128, 256, 0, stream>>>(partial, g1, be1, prm, GB, N);
    k_bn_relu<<<2048, 256, 0, stream>>>(aggbf, out, prm, N);
}

// Round 10
// 353.051 us; speedup vs baseline: 1.1324x; 1.1081x over previous
//
#include <hip/hip_runtime.h>
#include <stdint.h>

#define FIN 256
#define FHID 128
#define BN_EPS 1e-3f

typedef short bf16x8 __attribute__((ext_vector_type(8)));
typedef float f32x4 __attribute__((ext_vector_type(4)));

__device__ inline short f2bf(float f) {
    unsigned u = __float_as_uint(f);
    unsigned r = (u + 0x7FFFu + ((u >> 16) & 1u)) >> 16;   // RNE
    return (short)r;
}
__device__ inline float bflo(unsigned v) { return __uint_as_float(v << 16); }
__device__ inline float bfhi(unsigned v) { return __uint_as_float(v & 0xFFFF0000u); }
__device__ inline float bf2f(short s) {
    return __uint_as_float(((unsigned)(unsigned short)s) << 16);
}

#define DEG_SCALE 131072.0f          // 2^17 fixed point
#define DEG_INV   (1.0f / 131072.0f)

// ------- hist (LDS bucket counts) || W0,W1 -> bf16 transposed ----------------
__global__ __launch_bounds__(256) void k_histprep(const int* __restrict__ ei, int E,
                                                  int CB, int CHUNK, int nbuk,
                                                  unsigned* __restrict__ bcnt,
                                                  const float* __restrict__ W0,
                                                  const float* __restrict__ W1,
                                                  short* __restrict__ Wt0,
                                                  short* __restrict__ Wt1) {
    __shared__ unsigned hist[1024];
    if ((int)blockIdx.x < CB) {
        for (int i = threadIdx.x; i < nbuk; i += 256) hist[i] = 0;
        __syncthreads();
        const int e0 = blockIdx.x * CHUNK;
        const int e1 = min(e0 + CHUNK, E);
        for (int e = e0 + threadIdx.x; e < e1; e += 256)
            atomicAdd(&hist[ei[E + e] >> 7], 1u);
        __syncthreads();
        for (int k = threadIdx.x; k < nbuk; k += 256)
            bcnt[(size_t)blockIdx.x * nbuk + k] = hist[k];
    } else {
        int idx = ((int)blockIdx.x - CB) * 256 + threadIdx.x;
        if (idx < 32768) {            // W0: [256][128] -> Wt0 [128][256]
            int n = idx >> 8, k = idx & 255;
            Wt0[idx] = f2bf(W0[k * 128 + n]);
        } else {
            int j = idx - 32768;      // W1: [128][128] -> Wt1 [128][128]
            if (j < 16384) {
                int n = j >> 7, k = j & 127;
                Wt1[j] = f2bf(W1[k * 128 + n]);
            }
        }
    }
}

// ---------------- GEMM0: f32 x in, chunked A-prefetch ----------------
__global__ __launch_bounds__(256, 2) void k_gemm0(const float* __restrict__ X,
                                                  const short* __restrict__ Wt,
                                                  short* __restrict__ H, int nrows) {
    const int lane = threadIdx.x & 63;
    const int w = threadIdx.x >> 6;
    const int r0 = blockIdx.x * 32;
    const int n0 = w * 32;
    const int l15 = lane & 15;
    const int lk = (lane >> 4) * 8;

    int row0 = r0 + l15;        if (row0 >= nrows) row0 = nrows - 1;
    int row1 = r0 + 16 + l15;   if (row1 >= nrows) row1 = nrows - 1;
    const float* rp[2] = { X + (size_t)row0 * 256 + lk, X + (size_t)row1 * 256 + lk };

    f32x4 acc[2][2];
#pragma unroll
    for (int mf = 0; mf < 2; mf++)
#pragma unroll
        for (int nf = 0; nf < 2; nf++)
#pragma unroll
            for (int r = 0; r < 4; r++) acc[mf][nf][r] = 0.0f;

#pragma unroll
    for (int ch = 0; ch < 2; ch++) {
        float4 u[4][2][2];   // 16 loads in flight
#pragma unroll
        for (int mf = 0; mf < 2; mf++)
#pragma unroll
            for (int c = 0; c < 4; c++) {
                u[c][mf][0] = *reinterpret_cast<const float4*>(rp[mf] + (ch * 4 + c) * 32);
                u[c][mf][1] = *reinterpret_cast<const float4*>(rp[mf] + (ch * 4 + c) * 32 + 4);
            }
#pragma unroll
        for (int c = 0; c < 4; c++) {
            const int ks = ch * 4 + c;
            bf16x8 a[2];
#pragma unroll
            for (int mf = 0; mf < 2; mf++) {
                const float4 u0 = u[c][mf][0], u1 = u[c][mf][1];
                bf16x8 t;
                t[0] = f2bf(u0.x); t[1] = f2bf(u0.y); t[2] = f2bf(u0.z); t[3] = f2bf(u0.w);
                t[4] = f2bf(u1.x); t[5] = f2bf(u1.y); t[6] = f2bf(u1.z); t[7] = f2bf(u1.w);
                a[mf] = t;
            }
            const bf16x8 b0 = *reinterpret_cast<const bf16x8*>(
                Wt + (size_t)(n0 + l15) * 256 + ks * 32 + lk);
            const bf16x8 b1 = *reinterpret_cast<const bf16x8*>(
                Wt + (size_t)(n0 + 16 + l15) * 256 + ks * 32 + lk);
            acc[0][0] = __builtin_amdgcn_mfma_f32_16x16x32_bf16(a[0], b0, acc[0][0], 0, 0, 0);
            acc[1][0] = __builtin_amdgcn_mfma_f32_16x16x32_bf16(a[1], b0, acc[1][0], 0, 0, 0);
            acc[0][1] = __builtin_amdgcn_mfma_f32_16x16x32_bf16(a[0], b1, acc[0][1], 0, 0, 0);
            acc[1][1] = __builtin_amdgcn_mfma_f32_16x16x32_bf16(a[1], b1, acc[1][1], 0, 0, 0);
        }
    }

#pragma unroll
    for (int mf = 0; mf < 2; mf++) {
        const int rbase = r0 + mf * 16 + (lane >> 4) * 4;
#pragma unroll
        for (int r = 0; r < 4; r++) {
            const int row = rbase + r;
            if (row < nrows) {
#pragma unroll
                for (int nf = 0; nf < 2; nf++)
                    H[(size_t)row * 128 + n0 + nf * 16 + l15] = f2bf(acc[mf][nf][r]);
            }
        }
    }
}

// ---------------- GEMM1: bf16 agg in + BN0+ReLU fused ----------------
__global__ __launch_bounds__(256, 2) void k_gemm1(const short* __restrict__ X,
                                                  const short* __restrict__ Wt,
                                                  const float* __restrict__ prm,
                                                  short* __restrict__ H, int nrows) {
    const int lane = threadIdx.x & 63;
    const int w = threadIdx.x >> 6;
    const int r0 = blockIdx.x * 32;
    const int n0 = w * 32;
    const int l15 = lane & 15;
    const int lk = (lane >> 4) * 8;

    bf16x8 araw[4][2];
#pragma unroll
    for (int mf = 0; mf < 2; mf++) {
        int row = r0 + mf * 16 + l15;
        if (row >= nrows) row = nrows - 1;
        const short* rp = X + (size_t)row * 128 + lk;
#pragma unroll
        for (int ks = 0; ks < 4; ks++)
            araw[ks][mf] = *reinterpret_cast<const bf16x8*>(rp + ks * 32);
    }

    f32x4 acc[2][2];
#pragma unroll
    for (int mf = 0; mf < 2; mf++)
#pragma unroll
        for (int nf = 0; nf < 2; nf++)
#pragma unroll
            for (int r = 0; r < 4; r++) acc[mf][nf][r] = 0.0f;

#pragma unroll
    for (int ks = 0; ks < 4; ks++) {
        const int kb = ks * 32 + lk;
        const float4 sc0 = *reinterpret_cast<const float4*>(prm + kb);
        const float4 sc1 = *reinterpret_cast<const float4*>(prm + kb + 4);
        const float4 sh0 = *reinterpret_cast<const float4*>(prm + 128 + kb);
        const float4 sh1 = *reinterpret_cast<const float4*>(prm + 128 + kb + 4);
        bf16x8 a[2];
#pragma unroll
        for (int mf = 0; mf < 2; mf++) {
            const bf16x8 ar = araw[ks][mf];
            bf16x8 t;
            t[0] = f2bf(fmaxf(bf2f(ar[0]) * sc0.x + sh0.x, 0.f));
            t[1] = f2bf(fmaxf(bf2f(ar[1]) * sc0.y + sh0.y, 0.f));
            t[2] = f2bf(fmaxf(bf2f(ar[2]) * sc0.z + sh0.z, 0.f));
            t[3] = f2bf(fmaxf(bf2f(ar[3]) * sc0.w + sh0.w, 0.f));
            t[4] = f2bf(fmaxf(bf2f(ar[4]) * sc1.x + sh1.x, 0.f));
            t[5] = f2bf(fmaxf(bf2f(ar[5]) * sc1.y + sh1.y, 0.f));
            t[6] = f2bf(fmaxf(bf2f(ar[6]) * sc1.z + sh1.z, 0.f));
            t[7] = f2bf(fmaxf(bf2f(ar[7]) * sc1.w + sh1.w, 0.f));
            a[mf] = t;
        }
        const bf16x8 b0 = *reinterpret_cast<const bf16x8*>(
            Wt + (size_t)(n0 + l15) * 128 + kb);
        const bf16x8 b1 = *reinterpret_cast<const bf16x8*>(
            Wt + (size_t)(n0 + 16 + l15) * 128 + kb);
        acc[0][0] = __builtin_amdgcn_mfma_f32_16x16x32_bf16(a[0], b0, acc[0][0], 0, 0, 0);
        acc[1][0] = __builtin_amdgcn_mfma_f32_16x16x32_bf16(a[1], b0, acc[1][0], 0, 0, 0);
        acc[0][1] = __builtin_amdgcn_mfma_f32_16x16x32_bf16(a[0], b1, acc[0][1], 0, 0, 0);
        acc[1][1] = __builtin_amdgcn_mfma_f32_16x16x32_bf16(a[1], b1, acc[1][1], 0, 0, 0);
    }

#pragma unroll
    for (int mf = 0; mf < 2; mf++) {
        const int rbase = r0 + mf * 16 + (lane >> 4) * 4;
#pragma unroll
        for (int r = 0; r < 4; r++) {
            const int row = rbase + r;
            if (row < nrows) {
#pragma unroll
                for (int nf = 0; nf < 2; nf++)
                    H[(size_t)row * 128 + n0 + nf * 16 + l15] = f2bf(acc[mf][nf][r]);
            }
        }
    }
}

// ---------------- phase B: per-bucket scan of block counts (in-place) -------
__global__ __launch_bounds__(256) void k_phaseB(unsigned* __restrict__ bcnt,
                                                unsigned* __restrict__ btotal,
                                                int CB, int nbuk) {
    __shared__ unsigned lds[256];
    const int k = blockIdx.x;
    const int t = threadIdx.x;
    unsigned v = (t < CB) ? bcnt[(size_t)t * nbuk + k] : 0;
    lds[t] = v;
    __syncthreads();
    for (int off = 1; off < 256; off <<= 1) {
        unsigned add = (t >= off) ? lds[t - off] : 0;
        __syncthreads();
        lds[t] += add;
        __syncthreads();
    }
    if (t < CB) bcnt[(size_t)t * nbuk + k] = lds[t] - v;
    if (t == 255) btotal[k] = lds[255];
}

// ---------------- bucket base scan (single block) ----------------
__global__ __launch_bounds__(256) void k_bsum(const unsigned* __restrict__ btotal,
                                              unsigned* __restrict__ bbase,
                                              int nbuk, int E) {
    __shared__ unsigned lds[256];
    const int t = threadIdx.x;
    unsigned v[4];
    unsigned s = 0;
#pragma unroll
    for (int i = 0; i < 4; i++) {
        int j = t * 4 + i;
        v[i] = (j < nbuk) ? btotal[j] : 0;
        s += v[i];
    }
    lds[t] = s;
    __syncthreads();
    for (int off = 1; off < 256; off <<= 1) {
        unsigned add = (t >= off) ? lds[t - off] : 0;
        __syncthreads();
        lds[t] += add;
        __syncthreads();
    }
    unsigned run = lds[t] - s;
#pragma unroll
    for (int i = 0; i < 4; i++) {
        int j = t * 4 + i;
        if (j < nbuk) bbase[j] = run;
        run += v[i];
    }
    if (t == 255) bbase[nbuk] = (unsigned)E;
}

// ---------------- phase C: bucket-scatter edges (LDS cursors) ----------------
__global__ __launch_bounds__(256) void k_phaseC(const int* __restrict__ ei,
                                                const float* __restrict__ ew,
                                                int E, int CB, int CHUNK, int nbuk,
                                                const unsigned* __restrict__ bcur,
                                                const unsigned* __restrict__ bbase,
                                                int2* __restrict__ recs_mid) {
    __shared__ unsigned curs[1024];
    const int b = blockIdx.x;
    for (int k = threadIdx.x; k < nbuk; k += 256)
        curs[k] = bbase[k] + bcur[(size_t)b * nbuk + k];
    __syncthreads();
    const int e0 = b * CHUNK;
    const int e1 = min(e0 + CHUNK, E);
    for (int e = e0 + threadIdx.x; e < e1; e += 256) {
        int src = ei[e];
        int dst = ei[E + e];
        unsigned pos = atomicAdd(&curs[dst >> 7], 1u);
        recs_mid[pos] = make_int2(src | ((dst & 127) << 17), __float_as_int(ew[e]));
    }
}

// ---------------- phase D: per-bucket dst sort, dinv, rowptr, recs ----------
__global__ __launch_bounds__(256) void k_phaseD(const int2* __restrict__ recs_mid,
                                                const unsigned* __restrict__ bbase,
                                                float* __restrict__ dinv,
                                                int* __restrict__ rowptr,
                                                int2* __restrict__ recs,
                                                int n, int E) {
    __shared__ unsigned cnt[128], wsum[128], rank[128], sc[128], base[128];
    __shared__ float dloc[128];
    const int k = blockIdx.x;
    const int t = threadIdx.x;
    if (t < 128) { cnt[t] = 0; wsum[t] = 0; rank[t] = 0; }
    __syncthreads();
    const unsigned s0 = bbase[k], s1 = bbase[k + 1];
    for (unsigned i = s0 + t; i < s1; i += 256) {
        int2 r = recs_mid[i];
        int dl = (r.x >> 17) & 127;
        atomicAdd(&cnt[dl], 1u);
        atomicAdd(&wsum[dl], (unsigned)(__int_as_float(r.y) * DEG_SCALE));
    }
    __syncthreads();
    if (t < 128) sc[t] = cnt[t];
    __syncthreads();
    for (int off = 1; off < 128; off <<= 1) {
        unsigned add = (t < 128 && t >= off) ? sc[t - off] : 0;
        __syncthreads();
        if (t < 128) sc[t] += add;
        __syncthreads();
    }
    if (t < 128) {
        unsigned excl = sc[t] - cnt[t];
        base[t] = s0 + excl;
        int dst = k * 128 + t;
        if (dst < n) {
            float deg = (float)wsum[t] * DEG_INV + 1.0f;
            float dv = rsqrtf(deg);
            dloc[t] = dv;
            dinv[dst] = dv;
            rowptr[dst] = (int)(s0 + excl);
        }
    }
    if (k == 0 && t == 0) rowptr[n] = E;
    __syncthreads();
    for (unsigned i = s0 + t; i < s1; i += 256) {
        int2 r = recs_mid[i];
        int dl = (r.x >> 17) & 127;
        unsigned rr = atomicAdd(&rank[dl], 1u);
        float w2 = __int_as_float(r.y) * dloc[dl];     // ew * dinv[dst]
        recs[base[dl] + rr] = make_int2(r.x & 0x1FFFF, __float_as_int(w2));
    }
}

// ---------------- phase E: fold dinv[src] into rec weight ----------------
__global__ __launch_bounds__(256) void k_phaseE(int2* __restrict__ recs,
                                                const float* __restrict__ dinv, int E) {
    int i = blockIdx.x * 256 + threadIdx.x;
    if (i < E) {
        int2 r = recs[i];
        float w = __int_as_float(r.y) * dinv[r.x];
        recs[i] = make_int2(r.x, __float_as_int(w));
    }
}

// ------- gather + stats: one node per QUARTER-WAVE, 4-deep unroll -----------
// 16 lanes x uint4(8 bf16) cover 128 feats; 4 quarters = 4 independent nodes;
// per iteration the wave has 16 independent h-rows in flight.
__global__ __launch_bounds__(256) void k_gather_stats(const short* __restrict__ h,
                                                      short* __restrict__ aggbf,
                                                      const int* __restrict__ rowptr,
                                                      const int2* __restrict__ recs,
                                                      const float* __restrict__ dinv,
                                                      const float* __restrict__ bias,
                                                      float* __restrict__ partial,
                                                      int n, int nstreams) {
    __shared__ float lsum[4][128], lsq[4][128];
    const int w = threadIdx.x >> 6;
    const int lane = threadIdx.x & 63;
    const int q3 = lane >> 4;            // quarter id: which node stream
    const int f8 = (lane & 15) * 8;      // feature slice [f8, f8+8)
    const float4 bv0 = *reinterpret_cast<const float4*>(bias + f8);
    const float4 bv1 = *reinterpret_cast<const float4*>(bias + f8 + 4);
    float s[8], qq[8];
#pragma unroll
    for (int j = 0; j < 8; j++) { s[j] = 0.f; qq[j] = 0.f; }

    for (int node = blockIdx.x * 16 + w * 4 + q3; node < n; node += nstreams) {
        float a[8];
#pragma unroll
        for (int j = 0; j < 8; j++) a[j] = 0.f;
        int e = rowptr[node];
        const int end = rowptr[node + 1];
        for (; e + 4 <= end; e += 4) {
            const int2 r0 = recs[e];
            const int2 r1 = recs[e + 1];
            const int2 r2 = recs[e + 2];
            const int2 r3 = recs[e + 3];
            const uint4 v0 = *reinterpret_cast<const uint4*>(h + (size_t)r0.x * 128 + f8);
            const uint4 v1 = *reinterpret_cast<const uint4*>(h + (size_t)r1.x * 128 + f8);
            const uint4 v2 = *reinterpret_cast<const uint4*>(h + (size_t)r2.x * 128 + f8);
            const uint4 v3 = *reinterpret_cast<const uint4*>(h + (size_t)r3.x * 128 + f8);
            const float w0 = __int_as_float(r0.y);
            const float w1 = __int_as_float(r1.y);
            const float w2 = __int_as_float(r2.y);
            const float w3 = __int_as_float(r3.y);
            a[0] += bflo(v0.x) * w0; a[1] += bfhi(v0.x) * w0;
            a[2] += bflo(v0.y) * w0; a[3] += bfhi(v0.y) * w0;
            a[4] += bflo(v0.z) * w0; a[5] += bfhi(v0.z) * w0;
            a[6] += bflo(v0.w) * w0; a[7] += bfhi(v0.w) * w0;
            a[0] += bflo(v1.x) * w1; a[1] += bfhi(v1.x) * w1;
            a[2] += bflo(v1.y) * w1; a[3] += bfhi(v1.y) * w1;
            a[4] += bflo(v1.z) * w1; a[5] += bfhi(v1.z) * w1;
            a[6] += bflo(v1.w) * w1; a[7] += bfhi(v1.w) * w1;
            a[0] += bflo(v2.x) * w2; a[1] += bfhi(v2.x) * w2;
            a[2] += bflo(v2.y) * w2; a[3] += bfhi(v2.y) * w2;
            a[4] += bflo(v2.z) * w2; a[5] += bfhi(v2.z) * w2;
            a[6] += bflo(v2.w) * w2; a[7] += bfhi(v2.w) * w2;
            a[0] += bflo(v3.x) * w3; a[1] += bfhi(v3.x) * w3;
            a[2] += bflo(v3.y) * w3; a[3] += bfhi(v3.y) * w3;
            a[4] += bflo(v3.z) * w3; a[5] += bfhi(v3.z) * w3;
            a[6] += bflo(v3.w) * w3; a[7] += bfhi(v3.w) * w3;
        }
        for (; e < end; e++) {
            const int2 r = recs[e];
            const uint4 v = *reinterpret_cast<const uint4*>(h + (size_t)r.x * 128 + f8);
            const float w0 = __int_as_float(r.y);
            a[0] += bflo(v.x) * w0; a[1] += bfhi(v.x) * w0;
            a[2] += bflo(v.y) * w0; a[3] += bfhi(v.y) * w0;
            a[4] += bflo(v.z) * w0; a[5] += bfhi(v.z) * w0;
            a[6] += bflo(v.w) * w0; a[7] += bfhi(v.w) * w0;
        }
        const float di = dinv[node];
        const float sl = di * di;
        const uint4 hv = *reinterpret_cast<const uint4*>(h + (size_t)node * 128 + f8);
        float o[8];
        o[0] = a[0] + bflo(hv.x) * sl + bv0.x;
        o[1] = a[1] + bfhi(hv.x) * sl + bv0.y;
        o[2] = a[2] + bflo(hv.y) * sl + bv0.z;
        o[3] = a[3] + bfhi(hv.y) * sl + bv0.w;
        o[4] = a[4] + bflo(hv.z) * sl + bv1.x;
        o[5] = a[5] + bfhi(hv.z) * sl + bv1.y;
        o[6] = a[6] + bflo(hv.w) * sl + bv1.z;
        o[7] = a[7] + bfhi(hv.w) * sl + bv1.w;
        bf16x8 ob;
#pragma unroll
        for (int j = 0; j < 8; j++) ob[j] = f2bf(o[j]);
        *reinterpret_cast<bf16x8*>(aggbf + (size_t)node * 128 + f8) = ob;
#pragma unroll
        for (int j = 0; j < 8; j++) { s[j] += o[j]; qq[j] += o[j] * o[j]; }
    }

    // collapse the 4 quarters (same f8 slice at lane^16, lane^32)
#pragma unroll
    for (int j = 0; j < 8; j++) {
        s[j] += __shfl_xor(s[j], 16);  s[j] += __shfl_xor(s[j], 32);
        qq[j] += __shfl_xor(qq[j], 16); qq[j] += __shfl_xor(qq[j], 32);
    }
    if (q3 == 0) {
        *reinterpret_cast<float4*>(&lsum[w][f8]) = make_float4(s[0], s[1], s[2], s[3]);
        *reinterpret_cast<float4*>(&lsum[w][f8 + 4]) = make_float4(s[4], s[5], s[6], s[7]);
        *reinterpret_cast<float4*>(&lsq[w][f8]) = make_float4(qq[0], qq[1], qq[2], qq[3]);
        *reinterpret_cast<float4*>(&lsq[w][f8 + 4]) = make_float4(qq[4], qq[5], qq[6], qq[7]);
    }
    __syncthreads();
    const int t = threadIdx.x;
    if (t < 128) {
        float ps = lsum[0][t] + lsum[1][t] + lsum[2][t] + lsum[3][t];
        float pq = lsq[0][t] + lsq[1][t] + lsq[2][t] + lsq[3][t];
        partial[(size_t)blockIdx.x * 256 + t] = ps;
        partial[(size_t)blockIdx.x * 256 + 128 + t] = pq;
    }
}

// -------- stats reduce + BN params in one kernel (block = feature) ----------
__global__ __launch_bounds__(256) void k_stats_bn(const float* __restrict__ partial,
                                                  const float* __restrict__ g,
                                                  const float* __restrict__ beta,
                                                  float* __restrict__ prm,
                                                  int nblk, int n) {
    __shared__ float wsm[4], wqm[4];
    const int f = blockIdx.x;            // 0..127
    const int t = threadIdx.x;
    const int per = nblk / 256;          // 8
    float s = 0.f, q = 0.f;
    for (int i = 0; i < per; i++) {
        int p = t * per + i;
        s += partial[(size_t)p * 256 + f];
        q += partial[(size_t)p * 256 + 128 + f];
    }
#pragma unroll
    for (int off = 1; off < 64; off <<= 1) {
        s += __shfl_xor(s, off);
        q += __shfl_xor(q, off);
    }
    if ((t & 63) == 0) { wsm[t >> 6] = s; wqm[t >> 6] = q; }
    __syncthreads();
    if (t == 0) {
        float S = wsm[0] + wsm[1] + wsm[2] + wsm[3];
        float Q = wqm[0] + wqm[1] + wqm[2] + wqm[3];
        float inv_n = 1.0f / (float)n;
        float mu = S * inv_n;
        float var = Q * inv_n - mu * mu;
        float sc = rsqrtf(var + BN_EPS) * g[f];
        prm[f] = sc;
        prm[128 + f] = beta[f] - mu * sc;
    }
}

// ---------------- final BN apply + ReLU (bf16 agg -> f32 out) ----------------
__global__ __launch_bounds__(256) void k_bn_relu(const short* __restrict__ xbf,
                                                 float* __restrict__ y,
                                                 const float* __restrict__ prm, int n) {
    int idx = blockIdx.x * blockDim.x + threadIdx.x;
    const int total = n * 16;
    for (; idx < total; idx += gridDim.x * blockDim.x) {
        int node = idx >> 4;
        int f8 = (idx & 15) * 8;
        const uint4 v = *reinterpret_cast<const uint4*>(xbf + (size_t)node * 128 + f8);
        const float4 sc0 = *reinterpret_cast<const float4*>(prm + f8);
        const float4 sc1 = *reinterpret_cast<const float4*>(prm + f8 + 4);
        const float4 sh0 = *reinterpret_cast<const float4*>(prm + 128 + f8);
        const float4 sh1 = *reinterpret_cast<const float4*>(prm + 128 + f8 + 4);
        float4 o0, o1;
        o0.x = fmaxf(bflo(v.x) * sc0.x + sh0.x, 0.f);
        o0.y = fmaxf(bfhi(v.x) * sc0.y + sh0.y, 0.f);
        o0.z = fmaxf(bflo(v.y) * sc0.z + sh0.z, 0.f);
        o0.w = fmaxf(bfhi(v.y) * sc0.w + sh0.w, 0.f);
        o1.x = fmaxf(bflo(v.z) * sc1.x + sh1.x, 0.f);
        o1.y = fmaxf(bfhi(v.z) * sc1.y + sh1.y, 0.f);
        o1.z = fmaxf(bflo(v.w) * sc1.z + sh1.z, 0.f);
        o1.w = fmaxf(bfhi(v.w) * sc1.w + sh1.w, 0.f);
        float* yp = y + (size_t)node * 128 + f8;
        *reinterpret_cast<float4*>(yp) = o0;
        *reinterpret_cast<float4*>(yp + 4) = o1;
    }
}

extern "C" void kernel_launch(void* const* d_in, const int* in_sizes, int n_in,
                              void* d_out, int out_size, void* d_ws, size_t ws_size,
                              hipStream_t stream) {
    const float* x   = (const float*)d_in[0];
    const int*   ei  = (const int*)d_in[1];
    const float* ew  = (const float*)d_in[2];
    const float* W0  = (const float*)d_in[3];
    const float* b0  = (const float*)d_in[4];
    const float* g0  = (const float*)d_in[5];
    const float* be0 = (const float*)d_in[6];
    const float* W1  = (const float*)d_in[7];
    const float* b1  = (const float*)d_in[8];
    const float* g1  = (const float*)d_in[9];
    const float* be1 = (const float*)d_in[10];
    float* out = (float*)d_out;

    const int N = in_sizes[0] / FIN;          // 100000
    const int E = in_sizes[2];                // 1600000
    const int NBUK = (N + 127) >> 7;          // 782
    const int CB = 256;                       // hist chunks (<= 256 for phaseB)
    const int CHUNK = (E + CB - 1) / CB;      // 6250
    const int GB = 2048;                      // gather grid

    // workspace layout
    short* aggbf    = (short*)d_ws;                          // [N,128] bf16
    short* hbf      = aggbf + (size_t)N * 128;               // [N,128] bf16
    int2*  recs     = (int2*)(hbf + (size_t)N * 128);        // [E]
    int2*  recs_mid = recs + E;                              // [E]
    unsigned* bcnt  = (unsigned*)(recs_mid + E);             // [CB*NBUK]
    unsigned* btotal= bcnt + (size_t)CB * NBUK;              // [NBUK]
    unsigned* bbase = btotal + NBUK;                         // [NBUK+1]
    float* dinv     = (float*)(bbase + NBUK + 1);            // [N]
    int*   rowptr   = (int*)(dinv + N);                      // [N+1]
    float* prm      = (float*)(rowptr + N + 1);              // 256
    float* partial  = prm + 256;                             // [GB*256]

    // Wt staged in d_out (scratch until final bn_relu overwrites)
    short* Wt0 = (short*)d_out;            // [128][256] bf16
    short* Wt1 = Wt0 + 256 * 128;          // [128][128] bf16

    const int gemm_blocks = (N + 31) / 32;

    // ---- hist + weight prep, then GEMM0 straight from f32 x ----
    k_histprep<<<CB + 192, 256, 0, stream>>>(ei, E, CB, CHUNK, NBUK, bcnt,
                                             W0, W1, Wt0, Wt1);
    k_gemm0<<<gemm_blocks, 256, 0, stream>>>(x, Wt0, hbf, N);

    // ---- CSR build ----
    k_phaseB<<<NBUK, 256, 0, stream>>>(bcnt, btotal, CB, NBUK);
    k_bsum<<<1, 256, 0, stream>>>(btotal, bbase, NBUK, E);
    k_phaseC<<<CB, 256, 0, stream>>>(ei, ew, E, CB, CHUNK, NBUK, bcnt, bbase, recs_mid);
    k_phaseD<<<NBUK, 256, 0, stream>>>(recs_mid, bbase, dinv, rowptr, recs, N, E);
    k_phaseE<<<(E + 255) / 256, 256, 0, stream>>>(recs, dinv, E);

    // ---- layer 0 ----
    k_gather_stats<<<GB, 256, 0, stream>>>(hbf, aggbf, rowptr, recs, dinv, b0,
                                           partial, N, GB * 16);
    k_stats_bn<<<128, 256, 0, stream>>>(partial, g0, be0, prm, GB, N);

    // ---- layer 1 ----
    k_gemm1<<<gemm_blocks, 256, 0, stream>>>(aggbf, Wt1, prm, hbf, N);
    k_gather_stats<<<GB, 256, 0, stream>>>(hbf, aggbf, rowptr, recs, dinv, b1,
                                           partial, N, GB * 16);
    k_stats_bn<<<128, 256, 0, stream>>>(partial, g1, be1, prm, GB, N);
    k_bn_relu<<<2048, 256, 0, stream>>>(aggbf, out, prm, N);
}

// Round 11
// 321.722 us; speedup vs baseline: 1.2427x; 1.0974x over previous
//
#include <hip/hip_runtime.h>
#include <stdint.h>

#define FIN 256
#define FHID 128
#define BN_EPS 1e-3f

#ifndef USE_GLL
#if defined(__has_builtin)
#if __has_builtin(__builtin_amdgcn_global_load_lds)
#define USE_GLL 1
#else
#define USE_GLL 0
#endif
#else
#define USE_GLL 0
#endif
#endif

typedef short bf16x8 __attribute__((ext_vector_type(8)));
typedef float f32x4 __attribute__((ext_vector_type(4)));

__device__ inline short f2bf(float f) {
    unsigned u = __float_as_uint(f);
    unsigned r = (u + 0x7FFFu + ((u >> 16) & 1u)) >> 16;   // RNE
    return (short)r;
}
__device__ inline float bflo(unsigned v) { return __uint_as_float(v << 16); }
__device__ inline float bfhi(unsigned v) { return __uint_as_float(v & 0xFFFF0000u); }
__device__ inline float bf2f(short s) {
    return __uint_as_float(((unsigned)(unsigned short)s) << 16);
}

#define DEG_SCALE 131072.0f          // 2^17 fixed point
#define DEG_INV   (1.0f / 131072.0f)

// ------- hist (HB fine-grained blocks) || W0,W1 -> bf16 transposed ----------
__global__ __launch_bounds__(256) void k_histprep(const int* __restrict__ ei, int E,
                                                  int HB, int CHUNKH, int nbuk,
                                                  unsigned* __restrict__ bcnt,
                                                  const float* __restrict__ W0,
                                                  const float* __restrict__ W1,
                                                  short* __restrict__ Wt0,
                                                  short* __restrict__ Wt1) {
    __shared__ unsigned hist[1024];
    if ((int)blockIdx.x < HB) {
        for (int i = threadIdx.x; i < nbuk; i += 256) hist[i] = 0;
        __syncthreads();
        const int e0 = blockIdx.x * CHUNKH;
        const int e1 = min(e0 + CHUNKH, E);
        for (int e = e0 + threadIdx.x; e < e1; e += 256)
            atomicAdd(&hist[ei[E + e] >> 7], 1u);
        __syncthreads();
        for (int k = threadIdx.x; k < nbuk; k += 256)
            bcnt[(size_t)blockIdx.x * nbuk + k] = hist[k];
    } else {
        int idx = ((int)blockIdx.x - HB) * 256 + threadIdx.x;
        if (idx < 32768) {            // W0: [256][128] -> Wt0 [128][256]
            int n = idx >> 8, k = idx & 255;
            Wt0[idx] = f2bf(W0[k * 128 + n]);
        } else {
            int j = idx - 32768;      // W1: [128][128] -> Wt1 [128][128]
            if (j < 16384) {
                int n = j >> 7, k = j & 127;
                Wt1[j] = f2bf(W1[k * 128 + n]);
            }
        }
    }
}

// ---------------- GEMM0: f32 x staged to LDS via global_load_lds ------------
// LDS tile [32 rows][1KB], physical layout row-swizzled: logical byte c of
// row r lives at r*1024 + (c ^ ((r&7)<<4)).  Source pre-swizzled (rule 21).
__global__ __launch_bounds__(256) void k_gemm0(const float* __restrict__ X,
                                               const short* __restrict__ Wt,
                                               short* __restrict__ H, int nrows) {
    __shared__ float xs[8192];   // 32KB
    const int t = threadIdx.x;
    const int lane = t & 63;
    const int w = t >> 6;
    const int r0 = blockIdx.x * 32;
    const int l15 = lane & 15;
    const int q = lane >> 4;

    // ---- stage: wave w covers rows 8w..8w+7 (1KB each) ----
#pragma unroll
    for (int i = 0; i < 8; i++) {
        const int row = w * 8 + i;
        int grow = r0 + row; if (grow >= nrows) grow = nrows - 1;
        const char* gsrc = (const char*)(X + (size_t)grow * 256);
        const int swz = (row & 7) << 4;
#if USE_GLL
        __builtin_amdgcn_global_load_lds(gsrc + ((lane * 16) ^ swz),
                                         xs + row * 256, 16, 0, 0);
#else
        const float4 v = *reinterpret_cast<const float4*>(gsrc + ((lane * 16) ^ swz));
        *reinterpret_cast<float4*>((char*)xs + row * 1024 + lane * 16) = v;
#endif
    }
    __syncthreads();

    const int n0 = w * 32;
    const int swzr = (l15 & 7) << 4;

    f32x4 acc[2][2];
#pragma unroll
    for (int mf = 0; mf < 2; mf++)
#pragma unroll
        for (int nf = 0; nf < 2; nf++)
#pragma unroll
            for (int r = 0; r < 4; r++) acc[mf][nf][r] = 0.0f;

#pragma unroll
    for (int ks = 0; ks < 8; ks++) {
        const int cb = ks * 128 + q * 32;          // logical byte col of fragment
        bf16x8 a[2];
#pragma unroll
        for (int mf = 0; mf < 2; mf++) {
            const char* rb = (const char*)xs + (size_t)(mf * 16 + l15) * 1024;
            const float4 u0 = *reinterpret_cast<const float4*>(rb + (cb ^ swzr));
            const float4 u1 = *reinterpret_cast<const float4*>(rb + ((cb + 16) ^ swzr));
            bf16x8 tt;
            tt[0] = f2bf(u0.x); tt[1] = f2bf(u0.y); tt[2] = f2bf(u0.z); tt[3] = f2bf(u0.w);
            tt[4] = f2bf(u1.x); tt[5] = f2bf(u1.y); tt[6] = f2bf(u1.z); tt[7] = f2bf(u1.w);
            a[mf] = tt;
        }
        const bf16x8 b0 = *reinterpret_cast<const bf16x8*>(
            Wt + (size_t)(n0 + l15) * 256 + ks * 32 + q * 8);
        const bf16x8 b1 = *reinterpret_cast<const bf16x8*>(
            Wt + (size_t)(n0 + 16 + l15) * 256 + ks * 32 + q * 8);
        acc[0][0] = __builtin_amdgcn_mfma_f32_16x16x32_bf16(a[0], b0, acc[0][0], 0, 0, 0);
        acc[1][0] = __builtin_amdgcn_mfma_f32_16x16x32_bf16(a[1], b0, acc[1][0], 0, 0, 0);
        acc[0][1] = __builtin_amdgcn_mfma_f32_16x16x32_bf16(a[0], b1, acc[0][1], 0, 0, 0);
        acc[1][1] = __builtin_amdgcn_mfma_f32_16x16x32_bf16(a[1], b1, acc[1][1], 0, 0, 0);
    }

#pragma unroll
    for (int mf = 0; mf < 2; mf++) {
        const int rbase = r0 + mf * 16 + (lane >> 4) * 4;
#pragma unroll
        for (int r = 0; r < 4; r++) {
            const int row = rbase + r;
            if (row < nrows) {
#pragma unroll
                for (int nf = 0; nf < 2; nf++)
                    H[(size_t)row * 128 + n0 + nf * 16 + l15] = f2bf(acc[mf][nf][r]);
            }
        }
    }
}

// ---------------- GEMM1: bf16 agg staged to LDS + BN0+ReLU fused ------------
// LDS tile [32 rows][256B], same row-swizzle scheme.
__global__ __launch_bounds__(256) void k_gemm1(const short* __restrict__ X,
                                               const short* __restrict__ Wt,
                                               const float* __restrict__ prm,
                                               short* __restrict__ H, int nrows) {
    __shared__ short xs[4096];   // 8KB
    const int t = threadIdx.x;
    const int lane = t & 63;
    const int w = t >> 6;
    const int r0 = blockIdx.x * 32;
    const int l15 = lane & 15;
    const int q = lane >> 4;

    // ---- stage: wave w covers rows 8w..8w+7; call j covers 4 rows (1KB) ----
#pragma unroll
    for (int j = 0; j < 2; j++) {
        const int rbase = w * 8 + j * 4;
        const int row = rbase + q;               // per-lane row
        int grow = r0 + row; if (grow >= nrows) grow = nrows - 1;
        const char* gsrc = (const char*)(X + (size_t)grow * 128);
        const int swz = (row & 7) << 4;
#if USE_GLL
        __builtin_amdgcn_global_load_lds(gsrc + (((lane & 15) * 16) ^ swz),
                                         xs + rbase * 128, 16, 0, 0);
#else
        const uint4 v = *reinterpret_cast<const uint4*>(gsrc + (((lane & 15) * 16) ^ swz));
        *reinterpret_cast<uint4*>((char*)xs + rbase * 256 + lane * 16) = v;
#endif
    }
    __syncthreads();

    const int n0 = w * 32;
    const int swzr = (l15 & 7) << 4;

    f32x4 acc[2][2];
#pragma unroll
    for (int mf = 0; mf < 2; mf++)
#pragma unroll
        for (int nf = 0; nf < 2; nf++)
#pragma unroll
            for (int r = 0; r < 4; r++) acc[mf][nf][r] = 0.0f;

#pragma unroll
    for (int ks = 0; ks < 4; ks++) {
        const int kb = ks * 32 + q * 8;          // f32-elem index into prm
        const int cb = ks * 64 + q * 16;         // logical byte col in bf16 row
        const float4 sc0 = *reinterpret_cast<const float4*>(prm + kb);
        const float4 sc1 = *reinterpret_cast<const float4*>(prm + kb + 4);
        const float4 sh0 = *reinterpret_cast<const float4*>(prm + 128 + kb);
        const float4 sh1 = *reinterpret_cast<const float4*>(prm + 128 + kb + 4);
        bf16x8 a[2];
#pragma unroll
        for (int mf = 0; mf < 2; mf++) {
            const char* rb = (const char*)xs + (size_t)(mf * 16 + l15) * 256;
            const bf16x8 ar = *reinterpret_cast<const bf16x8*>(rb + (cb ^ swzr));
            bf16x8 tt;
            tt[0] = f2bf(fmaxf(bf2f(ar[0]) * sc0.x + sh0.x, 0.f));
            tt[1] = f2bf(fmaxf(bf2f(ar[1]) * sc0.y + sh0.y, 0.f));
            tt[2] = f2bf(fmaxf(bf2f(ar[2]) * sc0.z + sh0.z, 0.f));
            tt[3] = f2bf(fmaxf(bf2f(ar[3]) * sc0.w + sh0.w, 0.f));
            tt[4] = f2bf(fmaxf(bf2f(ar[4]) * sc1.x + sh1.x, 0.f));
            tt[5] = f2bf(fmaxf(bf2f(ar[5]) * sc1.y + sh1.y, 0.f));
            tt[6] = f2bf(fmaxf(bf2f(ar[6]) * sc1.z + sh1.z, 0.f));
            tt[7] = f2bf(fmaxf(bf2f(ar[7]) * sc1.w + sh1.w, 0.f));
            a[mf] = tt;
        }
        const bf16x8 b0 = *reinterpret_cast<const bf16x8*>(
            Wt + (size_t)(n0 + l15) * 128 + kb);
        const bf16x8 b1 = *reinterpret_cast<const bf16x8*>(
            Wt + (size_t)(n0 + 16 + l15) * 128 + kb);
        acc[0][0] = __builtin_amdgcn_mfma_f32_16x16x32_bf16(a[0], b0, acc[0][0], 0, 0, 0);
        acc[1][0] = __builtin_amdgcn_mfma_f32_16x16x32_bf16(a[1], b0, acc[1][0], 0, 0, 0);
        acc[0][1] = __builtin_amdgcn_mfma_f32_16x16x32_bf16(a[0], b1, acc[0][1], 0, 0, 0);
        acc[1][1] = __builtin_amdgcn_mfma_f32_16x16x32_bf16(a[1], b1, acc[1][1], 0, 0, 0);
    }

#pragma unroll
    for (int mf = 0; mf < 2; mf++) {
        const int rbase = r0 + mf * 16 + (lane >> 4) * 4;
#pragma unroll
        for (int r = 0; r < 4; r++) {
            const int row = rbase + r;
            if (row < nrows) {
#pragma unroll
                for (int nf = 0; nf < 2; nf++)
                    H[(size_t)row * 128 + n0 + nf * 16 + l15] = f2bf(acc[mf][nf][r]);
            }
        }
    }
}

// -------- phase B: per-bucket scan of HB block counts (4/thread) ------------
__global__ __launch_bounds__(256) void k_phaseB(unsigned* __restrict__ bcnt,
                                                unsigned* __restrict__ btotal,
                                                int HB, int nbuk) {
    __shared__ unsigned lds[256];
    const int k = blockIdx.x;
    const int t = threadIdx.x;
    unsigned v[4];
    unsigned s = 0;
#pragma unroll
    for (int i = 0; i < 4; i++) {
        int j = t * 4 + i;
        v[i] = (j < HB) ? bcnt[(size_t)j * nbuk + k] : 0;
        s += v[i];
    }
    lds[t] = s;
    __syncthreads();
    for (int off = 1; off < 256; off <<= 1) {
        unsigned add = (t >= off) ? lds[t - off] : 0;
        __syncthreads();
        lds[t] += add;
        __syncthreads();
    }
    unsigned run = lds[t] - s;
#pragma unroll
    for (int i = 0; i < 4; i++) {
        int j = t * 4 + i;
        if (j < HB) bcnt[(size_t)j * nbuk + k] = run;
        run += v[i];
    }
    if (t == 255) btotal[k] = lds[255];
}

// ---------------- bucket base scan (single block) ----------------
__global__ __launch_bounds__(256) void k_bsum(const unsigned* __restrict__ btotal,
                                              unsigned* __restrict__ bbase,
                                              int nbuk, int E) {
    __shared__ unsigned lds[256];
    const int t = threadIdx.x;
    unsigned v[4];
    unsigned s = 0;
#pragma unroll
    for (int i = 0; i < 4; i++) {
        int j = t * 4 + i;
        v[i] = (j < nbuk) ? btotal[j] : 0;
        s += v[i];
    }
    lds[t] = s;
    __syncthreads();
    for (int off = 1; off < 256; off <<= 1) {
        unsigned add = (t >= off) ? lds[t - off] : 0;
        __syncthreads();
        lds[t] += add;
        __syncthreads();
    }
    unsigned run = lds[t] - s;
#pragma unroll
    for (int i = 0; i < 4; i++) {
        int j = t * 4 + i;
        if (j < nbuk) bbase[j] = run;
        run += v[i];
    }
    if (t == 255) bbase[nbuk] = (unsigned)E;
}

// ------- phase C: bucket-scatter (256 blocks, each = `sub` hist chunks) -----
__global__ __launch_bounds__(256) void k_phaseC(const int* __restrict__ ei,
                                                const float* __restrict__ ew,
                                                int E, int CHUNKC, int nbuk, int sub,
                                                const unsigned* __restrict__ bcnt,
                                                const unsigned* __restrict__ bbase,
                                                int2* __restrict__ recs_mid) {
    __shared__ unsigned curs[1024];
    const int b = blockIdx.x;
    for (int k = threadIdx.x; k < nbuk; k += 256)
        curs[k] = bbase[k] + bcnt[(size_t)(b * sub) * nbuk + k];
    __syncthreads();
    const int e0 = b * CHUNKC;
    const int e1 = min(e0 + CHUNKC, E);
    for (int e = e0 + threadIdx.x; e < e1; e += 256) {
        int src = ei[e];
        int dst = ei[E + e];
        unsigned pos = atomicAdd(&curs[dst >> 7], 1u);
        recs_mid[pos] = make_int2(src | ((dst & 127) << 17), __float_as_int(ew[e]));
    }
}

// ---------------- phase D: per-bucket dst sort, dinv, rowptr, recs ----------
__global__ __launch_bounds__(256) void k_phaseD(const int2* __restrict__ recs_mid,
                                                const unsigned* __restrict__ bbase,
                                                float* __restrict__ dinv,
                                                int* __restrict__ rowptr,
                                                int2* __restrict__ recs,
                                                int n, int E) {
    __shared__ unsigned cnt[128], wsum[128], rank[128], sc[128], base[128];
    __shared__ float dloc[128];
    const int k = blockIdx.x;
    const int t = threadIdx.x;
    if (t < 128) { cnt[t] = 0; wsum[t] = 0; rank[t] = 0; }
    __syncthreads();
    const unsigned s0 = bbase[k], s1 = bbase[k + 1];
    for (unsigned i = s0 + t; i < s1; i += 256) {
        int2 r = recs_mid[i];
        int dl = (r.x >> 17) & 127;
        atomicAdd(&cnt[dl], 1u);
        atomicAdd(&wsum[dl], (unsigned)(__int_as_float(r.y) * DEG_SCALE));
    }
    __syncthreads();
    if (t < 128) sc[t] = cnt[t];
    __syncthreads();
    for (int off = 1; off < 128; off <<= 1) {
        unsigned add = (t < 128 && t >= off) ? sc[t - off] : 0;
        __syncthreads();
        if (t < 128) sc[t] += add;
        __syncthreads();
    }
    if (t < 128) {
        unsigned excl = sc[t] - cnt[t];
        base[t] = s0 + excl;
        int dst = k * 128 + t;
        if (dst < n) {
            float deg = (float)wsum[t] * DEG_INV + 1.0f;
            float dv = rsqrtf(deg);
            dloc[t] = dv;
            dinv[dst] = dv;
            rowptr[dst] = (int)(s0 + excl);
        }
    }
    if (k == 0 && t == 0) rowptr[n] = E;
    __syncthreads();
    for (unsigned i = s0 + t; i < s1; i += 256) {
        int2 r = recs_mid[i];
        int dl = (r.x >> 17) & 127;
        unsigned rr = atomicAdd(&rank[dl], 1u);
        float w2 = __int_as_float(r.y) * dloc[dl];     // ew * dinv[dst]
        recs[base[dl] + rr] = make_int2(r.x & 0x1FFFF, __float_as_int(w2));
    }
}

// ---------------- phase E: fold dinv[src] into rec weight ----------------
__global__ __launch_bounds__(256) void k_phaseE(int2* __restrict__ recs,
                                                const float* __restrict__ dinv, int E) {
    int i = blockIdx.x * 256 + threadIdx.x;
    if (i < E) {
        int2 r = recs[i];
        float w = __int_as_float(r.y) * dinv[r.x];
        recs[i] = make_int2(r.x, __float_as_int(w));
    }
}

// ------- gather + stats: one node per QUARTER-WAVE, 4-deep unroll -----------
__global__ __launch_bounds__(256) void k_gather_stats(const short* __restrict__ h,
                                                      short* __restrict__ aggbf,
                                                      const int* __restrict__ rowptr,
                                                      const int2* __restrict__ recs,
                                                      const float* __restrict__ dinv,
                                                      const float* __restrict__ bias,
                                                      float* __restrict__ partial,
                                                      int n, int nstreams) {
    __shared__ float lsum[4][128], lsq[4][128];
    const int w = threadIdx.x >> 6;
    const int lane = threadIdx.x & 63;
    const int q3 = lane >> 4;            // quarter id: which node stream
    const int f8 = (lane & 15) * 8;      // feature slice [f8, f8+8)
    const float4 bv0 = *reinterpret_cast<const float4*>(bias + f8);
    const float4 bv1 = *reinterpret_cast<const float4*>(bias + f8 + 4);
    float s[8], qq[8];
#pragma unroll
    for (int j = 0; j < 8; j++) { s[j] = 0.f; qq[j] = 0.f; }

    for (int node = blockIdx.x * 16 + w * 4 + q3; node < n; node += nstreams) {
        float a[8];
#pragma unroll
        for (int j = 0; j < 8; j++) a[j] = 0.f;
        int e = rowptr[node];
        const int end = rowptr[node + 1];
        for (; e + 4 <= end; e += 4) {
            const int2 r0 = recs[e];
            const int2 r1 = recs[e + 1];
            const int2 r2 = recs[e + 2];
            const int2 r3 = recs[e + 3];
            const uint4 v0 = *reinterpret_cast<const uint4*>(h + (size_t)r0.x * 128 + f8);
            const uint4 v1 = *reinterpret_cast<const uint4*>(h + (size_t)r1.x * 128 + f8);
            const uint4 v2 = *reinterpret_cast<const uint4*>(h + (size_t)r2.x * 128 + f8);
            const uint4 v3 = *reinterpret_cast<const uint4*>(h + (size_t)r3.x * 128 + f8);
            const float w0 = __int_as_float(r0.y);
            const float w1 = __int_as_float(r1.y);
            const float w2 = __int_as_float(r2.y);
            const float w3 = __int_as_float(r3.y);
            a[0] += bflo(v0.x) * w0; a[1] += bfhi(v0.x) * w0;
            a[2] += bflo(v0.y) * w0; a[3] += bfhi(v0.y) * w0;
            a[4] += bflo(v0.z) * w0; a[5] += bfhi(v0.z) * w0;
            a[6] += bflo(v0.w) * w0; a[7] += bfhi(v0.w) * w0;
            a[0] += bflo(v1.x) * w1; a[1] += bfhi(v1.x) * w1;
            a[2] += bflo(v1.y) * w1; a[3] += bfhi(v1.y) * w1;
            a[4] += bflo(v1.z) * w1; a[5] += bfhi(v1.z) * w1;
            a[6] += bflo(v1.w) * w1; a[7] += bfhi(v1.w) * w1;
            a[0] += bflo(v2.x) * w2; a[1] += bfhi(v2.x) * w2;
            a[2] += bflo(v2.y) * w2; a[3] += bfhi(v2.y) * w2;
            a[4] += bflo(v2.z) * w2; a[5] += bfhi(v2.z) * w2;
            a[6] += bflo(v2.w) * w2; a[7] += bfhi(v2.w) * w2;
            a[0] += bflo(v3.x) * w3; a[1] += bfhi(v3.x) * w3;
            a[2] += bflo(v3.y) * w3; a[3] += bfhi(v3.y) * w3;
            a[4] += bflo(v3.z) * w3; a[5] += bfhi(v3.z) * w3;
            a[6] += bflo(v3.w) * w3; a[7] += bfhi(v3.w) * w3;
        }
        for (; e < end; e++) {
            const int2 r = recs[e];
            const uint4 v = *reinterpret_cast<const uint4*>(h + (size_t)r.x * 128 + f8);
            const float w0 = __int_as_float(r.y);
            a[0] += bflo(v.x) * w0; a[1] += bfhi(v.x) * w0;
            a[2] += bflo(v.y) * w0; a[3] += bfhi(v.y) * w0;
            a[4] += bflo(v.z) * w0; a[5] += bfhi(v.z) * w0;
            a[6] += bflo(v.w) * w0; a[7] += bfhi(v.w) * w0;
        }
        const float di = dinv[node];
        const float sl = di * di;
        const uint4 hv = *reinterpret_cast<const uint4*>(h + (size_t)node * 128 + f8);
        float o[8];
        o[0] = a[0] + bflo(hv.x) * sl + bv0.x;
        o[1] = a[1] + bfhi(hv.x) * sl + bv0.y;
        o[2] = a[2] + bflo(hv.y) * sl + bv0.z;
        o[3] = a[3] + bfhi(hv.y) * sl + bv0.w;
        o[4] = a[4] + bflo(hv.z) * sl + bv1.x;
        o[5] = a[5] + bfhi(hv.z) * sl + bv1.y;
        o[6] = a[6] + bflo(hv.w) * sl + bv1.z;
        o[7] = a[7] + bfhi(hv.w) * sl + bv1.w;
        bf16x8 ob;
#pragma unroll
        for (int j = 0; j < 8; j++) ob[j] = f2bf(o[j]);
        *reinterpret_cast<bf16x8*>(aggbf + (size_t)node * 128 + f8) = ob;
#pragma unroll
        for (int j = 0; j < 8; j++) { s[j] += o[j]; qq[j] += o[j] * o[j]; }
    }

#pragma unroll
    for (int j = 0; j < 8; j++) {
        s[j] += __shfl_xor(s[j], 16);  s[j] += __shfl_xor(s[j], 32);
        qq[j] += __shfl_xor(qq[j], 16); qq[j] += __shfl_xor(qq[j], 32);
    }
    if (q3 == 0) {
        *reinterpret_cast<float4*>(&lsum[w][f8]) = make_float4(s[0], s[1], s[2], s[3]);
        *reinterpret_cast<float4*>(&lsum[w][f8 + 4]) = make_float4(s[4], s[5], s[6], s[7]);
        *reinterpret_cast<float4*>(&lsq[w][f8]) = make_float4(qq[0], qq[1], qq[2], qq[3]);
        *reinterpret_cast<float4*>(&lsq[w][f8 + 4]) = make_float4(qq[4], qq[5], qq[6], qq[7]);
    }
    __syncthreads();
    const int t = threadIdx.x;
    if (t < 128) {
        float ps = lsum[0][t] + lsum[1][t] + lsum[2][t] + lsum[3][t];
        float pq = lsq[0][t] + lsq[1][t] + lsq[2][t] + lsq[3][t];
        partial[(size_t)blockIdx.x * 256 + t] = ps;
        partial[(size_t)blockIdx.x * 256 + 128 + t] = pq;
    }
}

// -------- stats reduce + BN params in one kernel (block = feature) ----------
__global__ __launch_bounds__(256) void k_stats_bn(const float* __restrict__ partial,
                                                  const float* __restrict__ g,
                                                  const float* __restrict__ beta,
                                                  float* __restrict__ prm,
                                                  int nblk, int n) {
    __shared__ float wsm[4], wqm[4];
    const int f = blockIdx.x;            // 0..127
    const int t = threadIdx.x;
    const int per = nblk / 256;          // 8
    float s = 0.f, q = 0.f;
    for (int i = 0; i < per; i++) {
        int p = t * per + i;
        s += partial[(size_t)p * 256 + f];
        q += partial[(size_t)p * 256 + 128 + f];
    }
#pragma unroll
    for (int off = 1; off < 64; off <<= 1) {
        s += __shfl_xor(s, off);
        q += __shfl_xor(q, off);
    }
    if ((t & 63) == 0) { wsm[t >> 6] = s; wqm[t >> 6] = q; }
    __syncthreads();
    if (t == 0) {
        float S = wsm[0] + wsm[1] + wsm[2] + wsm[3];
        float Q = wqm[0] + wqm[1] + wqm[2] + wqm[3];
        float inv_n = 1.0f / (float)n;
        float mu = S * inv_n;
        float var = Q * inv_n - mu * mu;
        float sc = rsqrtf(var + BN_EPS) * g[f];
        prm[f] = sc;
        prm[128 + f] = beta[f] - mu * sc;
    }
}

// ---------------- final BN apply + ReLU (bf16 agg -> f32 out) ----------------
__global__ __launch_bounds__(256) void k_bn_relu(const short* __restrict__ xbf,
                                                 float* __restrict__ y,
                                                 const float* __restrict__ prm, int n) {
    int idx = blockIdx.x * blockDim.x + threadIdx.x;
    const int total = n * 16;
    for (; idx < total; idx += gridDim.x * blockDim.x) {
        int node = idx >> 4;
        int f8 = (idx & 15) * 8;
        const uint4 v = *reinterpret_cast<const uint4*>(xbf + (size_t)node * 128 + f8);
        const float4 sc0 = *reinterpret_cast<const float4*>(prm + f8);
        const float4 sc1 = *reinterpret_cast<const float4*>(prm + f8 + 4);
        const float4 sh0 = *reinterpret_cast<const float4*>(prm + 128 + f8);
        const float4 sh1 = *reinterpret_cast<const float4*>(prm + 128 + f8 + 4);
        float4 o0, o1;
        o0.x = fmaxf(bflo(v.x) * sc0.x + sh0.x, 0.f);
        o0.y = fmaxf(bfhi(v.x) * sc0.y + sh0.y, 0.f);
        o0.z = fmaxf(bflo(v.y) * sc0.z + sh0.z, 0.f);
        o0.w = fmaxf(bfhi(v.y) * sc0.w + sh0.w, 0.f);
        o1.x = fmaxf(bflo(v.z) * sc1.x + sh1.x, 0.f);
        o1.y = fmaxf(bfhi(v.z) * sc1.y + sh1.y, 0.f);
        o1.z = fmaxf(bflo(v.w) * sc1.z + sh1.z, 0.f);
        o1.w = fmaxf(bfhi(v.w) * sc1.w + sh1.w, 0.f);
        float* yp = y + (size_t)node * 128 + f8;
        *reinterpret_cast<float4*>(yp) = o0;
        *reinterpret_cast<float4*>(yp + 4) = o1;
    }
}

extern "C" void kernel_launch(void* const* d_in, const int* in_sizes, int n_in,
                              void* d_out, int out_size, void* d_ws, size_t ws_size,
                              hipStream_t stream) {
    const float* x   = (const float*)d_in[0];
    const int*   ei  = (const int*)d_in[1];
    const float* ew  = (const float*)d_in[2];
    const float* W0  = (const float*)d_in[3];
    const float* b0  = (const float*)d_in[4];
    const float* g0  = (const float*)d_in[5];
    const float* be0 = (const float*)d_in[6];
    const float* W1  = (const float*)d_in[7];
    const float* b1  = (const float*)d_in[8];
    const float* g1  = (const float*)d_in[9];
    const float* be1 = (const float*)d_in[10];
    float* out = (float*)d_out;

    const int N = in_sizes[0] / FIN;          // 100000
    const int E = in_sizes[2];                // 1600000
    const int NBUK = (N + 127) >> 7;          // 782
    const int HB = 1024;                      // fine-grained hist blocks
    const int CHUNKH = (E + HB - 1) / HB;     // 1563
    const int CBC = 256;                      // phaseC blocks (write locality)
    const int SUB = HB / CBC;                 // 4 hist chunks per C block
    const int CHUNKC = CHUNKH * SUB;          // 6252
    const int GB = 2048;                      // gather grid

    // workspace layout
    short* aggbf    = (short*)d_ws;                          // [N,128] bf16
    short* hbf      = aggbf + (size_t)N * 128;               // [N,128] bf16
    int2*  recs     = (int2*)(hbf + (size_t)N * 128);        // [E]
    int2*  recs_mid = recs + E;                              // [E]
    unsigned* bcnt  = (unsigned*)(recs_mid + E);             // [HB*NBUK]
    unsigned* btotal= bcnt + (size_t)HB * NBUK;              // [NBUK]
    unsigned* bbase = btotal + NBUK;                         // [NBUK+1]
    float* dinv     = (float*)(bbase + NBUK + 1);            // [N]
    int*   rowptr   = (int*)(dinv + N);                      // [N+1]
    float* prm      = (float*)(rowptr + N + 1);              // 256
    float* partial  = prm + 256;                             // [GB*256]

    // Wt staged in d_out (scratch until final bn_relu overwrites)
    short* Wt0 = (short*)d_out;            // [128][256] bf16
    short* Wt1 = Wt0 + 256 * 128;          // [128][128] bf16

    const int gemm_blocks = (N + 31) / 32;

    // ---- hist + weight prep, then LDS-staged GEMM0 from f32 x ----
    k_histprep<<<HB + 192, 256, 0, stream>>>(ei, E, HB, CHUNKH, NBUK, bcnt,
                                             W0, W1, Wt0, Wt1);
    k_gemm0<<<gemm_blocks, 256, 0, stream>>>(x, Wt0, hbf, N);

    // ---- CSR build ----
    k_phaseB<<<NBUK, 256, 0, stream>>>(bcnt, btotal, HB, NBUK);
    k_bsum<<<1, 256, 0, stream>>>(btotal, bbase, NBUK, E);
    k_phaseC<<<CBC, 256, 0, stream>>>(ei, ew, E, CHUNKC, NBUK, SUB, bcnt, bbase, recs_mid);
    k_phaseD<<<NBUK, 256, 0, stream>>>(recs_mid, bbase, dinv, rowptr, recs, N, E);
    k_phaseE<<<(E + 255) / 256, 256, 0, stream>>>(recs, dinv, E);

    // ---- layer 0 ----
    k_gather_stats<<<GB, 256, 0, stream>>>(hbf, aggbf, rowptr, recs, dinv, b0,
                                           partial, N, GB * 16);
    k_stats_bn<<<128, 256, 0, stream>>>(partial, g0, be0, prm, GB, N);

    // ---- layer 1 ----
    k_gemm1<<<gemm_blocks, 256, 0, stream>>>(aggbf, Wt1, prm, hbf, N);
    k_gather_stats<<<GB, 256, 0, stream>>>(hbf, aggbf, rowptr, recs, dinv, b1,
                                           partial, N, GB * 16);
    k_stats_bn<<<128, 256, 0, stream>>>(partial, g1, be1, prm, GB, N);
    k_bn_relu<<<2048, 256, 0, stream>>>(aggbf, out, prm, N);
}